// Round 3
// baseline (1231.667 us; speedup 1.0000x reference)
//
#include <hip/hip_runtime.h>
#include <math.h>

// ---------------------------------------------------------------------------
// MultiTopologySurrogate: fused bf16-MFMA pipeline for MI355X (gfx950)
// ---------------------------------------------------------------------------

using bf16x8 = __attribute__((ext_vector_type(8))) short;
using f32x4  = __attribute__((ext_vector_type(4))) float;

static __device__ __forceinline__ short f2bf(float f) {
  union { float f; unsigned u; } v; v.f = f;
  unsigned r = v.u + 0x7fffu + ((v.u >> 16) & 1u);  // RNE
  return (short)(r >> 16);
}
static __device__ __forceinline__ float bf2f(short s) {
  union { unsigned u; float f; } v; v.u = ((unsigned)(unsigned short)s) << 16;
  return v.f;
}
static __device__ __forceinline__ float gelu_exact(float x) {
  return 0.5f * x * (1.f + erff(x * 0.70710678118654752f));
}

// --------------------------- bucket-by-id kernels ---------------------------
__global__ void k_zero(int* c) { if (threadIdx.x < 8) c[threadIdx.x] = 0; }

__global__ void k_count(const int* __restrict__ ids, int* __restrict__ cnt) {
  int i = blockIdx.x * 256 + threadIdx.x;
  if (i < 8192) atomicAdd(&cnt[ids[i]], 1);
}

__global__ void k_assign(const int* __restrict__ ids, const int* __restrict__ cnt,
                         int* __restrict__ cur, int* __restrict__ perm) {
  int i = blockIdx.x * 256 + threadIdx.x;
  if (i >= 8192) return;
  int t = ids[i];
  int base = 0;
  if (t > 0) base += cnt[0];
  if (t > 1) base += cnt[1];
  int pos = base + atomicAdd(&cur[t], 1);
  perm[pos] = i;
}

// --------------------------- weight prep (fp32 -> bf16 B^T) -----------------
// Wt[t][n][kpad] = (k<K) ? W[t][k][n] : 0
__global__ void prep_wt(const float* __restrict__ W, short* __restrict__ Wt,
                        int K, int N, int Kpad, int batch) {
  int i = blockIdx.x * 256 + threadIdx.x;
  int per = N * Kpad;
  int tot = per * batch;
  if (i >= tot) return;
  int t = i / per, j = i - t * per;
  int n = j / Kpad, k = j - n * Kpad;
  float v = (k < K) ? W[(size_t)t * K * N + (size_t)k * N + n] : 0.f;
  Wt[i] = f2bf(v);
}

// cw2p[c_out][tap*32 + c_in] = cw2[c_out][c_in][tap]   (K=160 flattened)
__global__ void prep_cw2(const float* __restrict__ cw2, short* __restrict__ cw2p) {
  int i = blockIdx.x * 256 + threadIdx.x;
  if (i >= 32 * 160) return;
  int co = i / 160, j = i - co * 160;
  int tap = j >> 5, ci = j & 31;
  cw2p[i] = f2bf(cw2[(co * 32 + ci) * 5 + tap]);
}

// --------------------------- input featurization ----------------------------
// xb[row][64] bf16: cols 0..5 normalized params, 6..37 emb[id], 38..63 zero
__global__ void build_x(const float* __restrict__ params, const float* __restrict__ emb,
                        const int* __restrict__ ids, short* __restrict__ xb) {
  int i = blockIdx.x * 256 + threadIdx.x;
  if (i >= 8192 * 64) return;
  int row = i >> 6, c = i & 63;
  float v;
  const float lo[6] = {1e-05f, 4.7e-05f, 2.0f, 5.0f, 50000.0f, 0.2f};
  const float hi[6] = {0.00047f, 0.001f, 100.0f, 24.0f, 500000.0f, 0.8f};
  const int lg[6] = {1, 1, 0, 0, 1, 0};
  if (c < 6) {
    float pv = params[row * 6 + c];
    if (lg[c]) v = (logf(pv) - logf(lo[c])) / (logf(hi[c]) - logf(lo[c]));
    else       v = (pv - lo[c]) / (hi[c] - lo[c]);
    v = fminf(fmaxf(v, 0.f), 1.f);
  } else if (c < 38) {
    v = emb[ids[row] * 32 + (c - 6)];
  } else v = 0.f;
  xb[i] = f2bf(v);
}

// --------------------------- generic fused GEMM -----------------------------
// out[b][n] = (opt LN)(opt GELU)( A[b][:] @ W + bias )
// A: bf16 [B][K] row-major. Wt: bf16 [T?][N][K] (B^T). 32 rows/block, 8 waves.
// MFMA 16x16x32: A lane l -> A[l&15][(l>>4)*8+j]; B lane l -> B[(l>>4)*8+j][l&15];
// D: col=l&15, row=(l>>4)*4+reg  (verified mapping).
template<int K, int N, int NTW, bool DO_LN, bool DO_GELU, bool OUT_F32, bool GATHER>
__global__ __launch_bounds__(512) void gemm_fused(
    const short* __restrict__ A, const short* __restrict__ Wt,
    const float* __restrict__ bias, const float* __restrict__ gam,
    const float* __restrict__ bet, void* __restrict__ outp,
    const int* __restrict__ perm, const int* __restrict__ ids) {
  const int tid = threadIdx.x;
  const int wave = tid >> 6;
  const int lane = tid & 63;
  const int g16 = lane >> 4;
  const int l16 = lane & 15;
  const int rowBase = blockIdx.x * 32;
  const int colBase = wave * (NTW * 16);

  __shared__ int sPerm[32];
  __shared__ int sId[32];
  __shared__ int sFlag[3];
  __shared__ float sPart[32][8][2];
  __shared__ float sStat[32][2];

  if (GATHER) {
    if (tid < 32) {
      int pr = perm[rowBase + tid];
      sPerm[tid] = pr;
      sId[tid] = ids[pr];
    }
    __syncthreads();
    if (tid < 3) {
      int f = 0;
      for (int i = 0; i < 32; ++i) f |= (sId[i] == tid) ? 1 : 0;
      sFlag[tid] = f;
    }
    __syncthreads();
  }

  size_t aoff[2];
#pragma unroll
  for (int mt = 0; mt < 2; ++mt) {
    int lrow = mt * 16 + l16;
    int arow = GATHER ? sPerm[lrow] : (rowBase + lrow);
    aoff[mt] = (size_t)arow * K + g16 * 8;
  }
  size_t boff[NTW];
#pragma unroll
  for (int nt = 0; nt < NTW; ++nt) {
    int n = colBase + nt * 16 + l16;
    boff[nt] = (size_t)n * K + g16 * 8;
  }

  const f32x4 vzero = {0.f, 0.f, 0.f, 0.f};
  const int TMAX = GATHER ? 3 : 1;
  for (int t = 0; t < TMAX; ++t) {
    if (GATHER && !sFlag[t]) continue;
    const short* Wtt = Wt + (GATHER ? (size_t)t * N * K : 0);
    const float* bt = bias + (GATHER ? t * N : 0);

    f32x4 acc[2][NTW];
#pragma unroll
    for (int mt = 0; mt < 2; ++mt)
#pragma unroll
      for (int nt = 0; nt < NTW; ++nt) acc[mt][nt] = vzero;

    for (int kk = 0; kk < K / 32; ++kk) {
      bf16x8 a0 = *(const bf16x8*)(A + aoff[0] + kk * 32);
      bf16x8 a1 = *(const bf16x8*)(A + aoff[1] + kk * 32);
#pragma unroll
      for (int nt = 0; nt < NTW; ++nt) {
        bf16x8 bq = *(const bf16x8*)(Wtt + boff[nt] + kk * 32);
        acc[0][nt] = __builtin_amdgcn_mfma_f32_16x16x32_bf16(a0, bq, acc[0][nt], 0, 0, 0);
        acc[1][nt] = __builtin_amdgcn_mfma_f32_16x16x32_bf16(a1, bq, acc[1][nt], 0, 0, 0);
      }
    }

    // bias add (must precede LN stats: reference is ln(x@W + b))
    float bv[NTW];
#pragma unroll
    for (int nt = 0; nt < NTW; ++nt) bv[nt] = bt[colBase + nt * 16 + l16];
#pragma unroll
    for (int mt = 0; mt < 2; ++mt)
#pragma unroll
      for (int nt = 0; nt < NTW; ++nt)
#pragma unroll
        for (int r = 0; r < 4; ++r) acc[mt][nt][r] += bv[nt];

    if (DO_LN) {
#pragma unroll
      for (int mt = 0; mt < 2; ++mt) {
#pragma unroll
        for (int r = 0; r < 4; ++r) {
          float s = 0.f, q = 0.f;
#pragma unroll
          for (int nt = 0; nt < NTW; ++nt) {
            float x = acc[mt][nt][r];
            s += x; q += x * x;
          }
#pragma unroll
          for (int m = 1; m < 16; m <<= 1) {
            s += __shfl_xor(s, m);
            q += __shfl_xor(q, m);
          }
          if (l16 == 0) {
            int row = mt * 16 + g16 * 4 + r;
            sPart[row][wave][0] = s;
            sPart[row][wave][1] = q;
          }
        }
      }
      __syncthreads();
      if (tid < 32) {
        float s = 0.f, q = 0.f;
#pragma unroll
        for (int w = 0; w < 8; ++w) { s += sPart[tid][w][0]; q += sPart[tid][w][1]; }
        float mean = s / (float)N;
        float var = q / (float)N - mean * mean;
        sStat[tid][0] = mean;
        sStat[tid][1] = rsqrtf(var + 1e-5f);
      }
      __syncthreads();
    }

    float gv[NTW], bev[NTW];
    if (DO_LN) {
#pragma unroll
      for (int nt = 0; nt < NTW; ++nt) {
        int c = colBase + nt * 16 + l16;
        gv[nt] = gam[c];
        bev[nt] = bet[c];
      }
    }

#pragma unroll
    for (int mt = 0; mt < 2; ++mt)
#pragma unroll
      for (int nt = 0; nt < NTW; ++nt) {
        int col = colBase + nt * 16 + l16;
#pragma unroll
        for (int r = 0; r < 4; ++r) {
          int row = mt * 16 + g16 * 4 + r;
          if (GATHER && sId[row] != t) continue;
          float x = acc[mt][nt][r];
          if (DO_LN) x = (x - sStat[row][0]) * sStat[row][1] * gv[nt] + bev[nt];
          if (DO_GELU) x = gelu_exact(x);
          size_t grow = GATHER ? (size_t)sPerm[row] : (size_t)(rowBase + row);
          if (OUT_F32) ((float*)outp)[grow * N + col] = x;
          else ((short*)outp)[grow * N + col] = f2bf(x);
        }
      }
  }
}

// --------------------------- conv stack ------------------------------------
// One block per batch row. conv1 (1->32,k7) VALU; conv2 (32->32,k5) implicit
// GEMM via MFMA (M=32, N=512, K=160=tap*32+c_in); conv3 (32->1,k3) VALU.
// y LDS: [row][c] bf16, row stride 64B, XOR swizzle ((r&3)<<4) on byte addr.
// y1 rows = t+2 (pads 0,1,514,515); y2 reuses buffer, rows = t+1 (pads 0,513).
__global__ __launch_bounds__(256) void conv_kernel(
    const float* __restrict__ w6, const float* __restrict__ cw1,
    const float* __restrict__ cb1, const short* __restrict__ cw2p,
    const float* __restrict__ cb2, const float* __restrict__ cw3,
    const float* __restrict__ cb3, const float* __restrict__ scales,
    const int* __restrict__ ids, float* __restrict__ out) {
  const int b = blockIdx.x;
  const int tid = threadIdx.x;
  const int wave = tid >> 6, lane = tid & 63;
  const int g16 = lane >> 4, l16 = lane & 15;

  __shared__ float sw[520];                 // w padded by 3 each side (idx t+3)
  __shared__ __align__(16) short y[516 * 32];
  __shared__ float scw1[224];
  __shared__ float scb1[32];
  __shared__ float scw3[96];

  const float* wr = w6 + (size_t)b * 512;
  for (int i = tid; i < 518; i += 256) {
    int t = i - 3;
    sw[i] = (t >= 0 && t < 512) ? wr[t] : 0.f;
  }
  if (tid < 224) scw1[tid] = cw1[tid];
  if (tid < 32) scb1[tid] = cb1[tid];
  if (tid >= 32 && tid < 128) scw3[tid - 32] = cw3[tid - 32];
  if (tid < 128) {  // zero y1 pad rows 0,1,514,515
    int rr = tid >> 5;
    int r = (rr < 2) ? rr : (512 + rr);
    int c = tid & 31;
    int byte = (r << 6) + ((c << 1) ^ ((r & 3) << 4));
    *(short*)((char*)y + byte) = 0;
  }
  __syncthreads();

  // conv1 + gelu -> y1[t+2][c]
  for (int it = 0; it < 64; ++it) {
    int idx = tid + it * 256;
    int c = idx & 31, t = idx >> 5;
    float s = scb1[c];
#pragma unroll
    for (int k = 0; k < 7; ++k) s += scw1[c * 7 + k] * sw[t + k];
    s = gelu_exact(s);
    int r = t + 2;
    int byte = (r << 6) + ((c << 1) ^ ((r & 3) << 4));
    *(short*)((char*)y + byte) = f2bf(s);
  }
  __syncthreads();

  // conv2 via MFMA
  bf16x8 afr[2][5];
#pragma unroll
  for (int mt = 0; mt < 2; ++mt)
#pragma unroll
    for (int kk = 0; kk < 5; ++kk)
      afr[mt][kk] = *(const bf16x8*)(cw2p + (mt * 16 + l16) * 160 + kk * 32 + g16 * 8);

  const f32x4 vzero = {0.f, 0.f, 0.f, 0.f};
  f32x4 acc[2][8];
#pragma unroll
  for (int mt = 0; mt < 2; ++mt)
#pragma unroll
    for (int nt = 0; nt < 8; ++nt) acc[mt][nt] = vzero;

  const int ntBase = wave * 8;
#pragma unroll
  for (int kk = 0; kk < 5; ++kk) {
#pragma unroll
    for (int nt = 0; nt < 8; ++nt) {
      int r = (ntBase + nt) * 16 + l16 + kk;  // y1 row = t + (kk-2) + 2
      int byte = (r << 6) + ((g16 << 4) ^ ((r & 3) << 4));
      bf16x8 bq = *(const bf16x8*)((char*)y + byte);
      acc[0][nt] = __builtin_amdgcn_mfma_f32_16x16x32_bf16(afr[0][kk], bq, acc[0][nt], 0, 0, 0);
      acc[1][nt] = __builtin_amdgcn_mfma_f32_16x16x32_bf16(afr[1][kk], bq, acc[1][nt], 0, 0, 0);
    }
  }
  __syncthreads();  // all y1 reads complete before overwrite

  if (tid < 64) {  // zero y2 pad rows 0, 513
    int r = (tid < 32) ? 0 : 513;
    int c = tid & 31;
    int byte = (r << 6) + ((c << 1) ^ ((r & 3) << 4));
    *(short*)((char*)y + byte) = 0;
  }
  // y2[t+1][c_out] = gelu(acc + cb2)
#pragma unroll
  for (int mt = 0; mt < 2; ++mt)
#pragma unroll
    for (int nt = 0; nt < 8; ++nt) {
      int t = (ntBase + nt) * 16 + l16;
      int c0 = mt * 16 + g16 * 4;
      union { short s[4]; unsigned u[2]; } pk;
#pragma unroll
      for (int r = 0; r < 4; ++r) {
        float x = acc[mt][nt][r] + cb2[c0 + r];
        pk.s[r] = f2bf(gelu_exact(x));
      }
      int r2 = t + 1;
      int byte = (r2 << 6) + ((c0 << 1) ^ ((r2 & 3) << 4));
      *(unsigned*)((char*)y + byte) = pk.u[0];
      *(unsigned*)((char*)y + byte + 4) = pk.u[1];
    }
  __syncthreads();

  // conv3 + residual + scale
  const float scale = scales[ids[b]];
  const float c3b = cb3[0];
  for (int it = 0; it < 2; ++it) {
    int t = tid + it * 256;
    float s = c3b;
#pragma unroll
    for (int k = 0; k < 3; ++k) {
      int r = t + k;  // y2 row for position t+k-1
#pragma unroll
      for (int c = 0; c < 32; ++c) {
        int byte = (r << 6) + ((c << 1) ^ ((r & 3) << 4));
        s += scw3[c * 3 + k] * bf2f(*(const short*)((const char*)y + byte));
      }
    }
    out[(size_t)b * 512 + t] = (wr[t] + s) * scale;
  }
}

// --------------------------- launch ----------------------------------------
extern "C" void kernel_launch(void* const* d_in, const int* in_sizes, int n_in,
                              void* d_out, int out_size, void* d_ws, size_t ws_size,
                              hipStream_t stream) {
  (void)in_sizes; (void)n_in; (void)out_size; (void)ws_size;
  const float* params = (const float*)d_in[0];
  const float* emb    = (const float*)d_in[1];
  const float* W1  = (const float*)d_in[2];
  const float* b1  = (const float*)d_in[3];
  const float* g1  = (const float*)d_in[4];
  const float* be1 = (const float*)d_in[5];
  const float* W2  = (const float*)d_in[6];
  const float* b2  = (const float*)d_in[7];
  const float* g2  = (const float*)d_in[8];
  const float* be2 = (const float*)d_in[9];
  const float* W3  = (const float*)d_in[10];
  const float* b3  = (const float*)d_in[11];
  const float* g3  = (const float*)d_in[12];
  const float* be3 = (const float*)d_in[13];
  const float* Wh  = (const float*)d_in[14];
  const float* bh  = (const float*)d_in[15];
  const float* Wd1 = (const float*)d_in[16];
  const float* bd1 = (const float*)d_in[17];
  const float* Wd2 = (const float*)d_in[18];
  const float* bd2 = (const float*)d_in[19];
  const float* cw1 = (const float*)d_in[20];
  const float* cb1 = (const float*)d_in[21];
  const float* cw2 = (const float*)d_in[22];
  const float* cb2 = (const float*)d_in[23];
  const float* cw3 = (const float*)d_in[24];
  const float* cb3 = (const float*)d_in[25];
  const float* scales = (const float*)d_in[26];
  const int* ids = (const int*)d_in[27];
  float* out = (float*)d_out;

  char* ws = (char*)d_ws;
  size_t off = 0;
  auto alloc = [&](size_t bytes) {
    size_t r = off;
    off += (bytes + 255) & ~(size_t)255;
    return r;
  };
  short* W1t  = (short*)(ws + alloc((size_t)512 * 64 * 2));
  short* W2t  = (short*)(ws + alloc((size_t)512 * 512 * 2));
  short* W3t  = (short*)(ws + alloc((size_t)1024 * 512 * 2));
  short* Wht  = (short*)(ws + alloc((size_t)3 * 512 * 1024 * 2));
  short* Wd1t = (short*)(ws + alloc((size_t)512 * 512 * 2));
  short* Wd2t = (short*)(ws + alloc((size_t)512 * 512 * 2));
  short* cw2p = (short*)(ws + alloc((size_t)32 * 160 * 2));
  short* xb   = (short*)(ws + alloc((size_t)8192 * 64 * 2));
  short* bufP = (short*)(ws + alloc((size_t)8192 * 512 * 2));
  short* bufQ = (short*)(ws + alloc((size_t)8192 * 512 * 2));
  short* bufF = (short*)(ws + alloc((size_t)8192 * 1024 * 2));  // feat, later w6 (fp32)
  int*   cntb = (int*)(ws + alloc(64));
  int*   permb = (int*)(ws + alloc((size_t)8192 * 4));
  float* w6 = (float*)bufF;  // feat is dead once GEMM4 completes

  auto gp = [](long tot) { return (int)((tot + 255) / 256); };

  // bucket rows by topology id
  k_zero<<<1, 64, 0, stream>>>(cntb);
  k_count<<<32, 256, 0, stream>>>(ids, cntb);
  k_assign<<<32, 256, 0, stream>>>(ids, cntb, cntb + 4, permb);

  // weight prep (fp32 -> bf16 B^T layout)
  prep_wt<<<gp(512 * 64), 256, 0, stream>>>(W1, W1t, 38, 512, 64, 1);
  prep_wt<<<gp(512 * 512), 256, 0, stream>>>(W2, W2t, 512, 512, 512, 1);
  prep_wt<<<gp(1024 * 512), 256, 0, stream>>>(W3, W3t, 512, 1024, 512, 1);
  prep_wt<<<gp(3L * 512 * 1024), 256, 0, stream>>>(Wh, Wht, 1024, 512, 1024, 3);
  prep_wt<<<gp(512 * 512), 256, 0, stream>>>(Wd1, Wd1t, 512, 512, 512, 1);
  prep_wt<<<gp(512 * 512), 256, 0, stream>>>(Wd2, Wd2t, 512, 512, 512, 1);
  prep_cw2<<<gp(32 * 160), 256, 0, stream>>>(cw2, cw2p);

  build_x<<<gp(8192L * 64), 256, 0, stream>>>(params, emb, ids, xb);

  // L1: x(64) -> 512, LN+gelu
  gemm_fused<64, 512, 4, true, true, false, false>
      <<<256, 512, 0, stream>>>(xb, W1t, b1, g1, be1, bufP, nullptr, nullptr);
  // L2: 512 -> 512, LN+gelu
  gemm_fused<512, 512, 4, true, true, false, false>
      <<<256, 512, 0, stream>>>(bufP, W2t, b2, g2, be2, bufQ, nullptr, nullptr);
  // L3: 512 -> 1024, LN+gelu -> feat
  gemm_fused<512, 1024, 8, true, true, false, false>
      <<<256, 512, 0, stream>>>(bufQ, W3t, b3, g3, be3, bufF, nullptr, nullptr);
  // L4: gathered per-topology 1024 -> 512 (+bh), bucketed rows
  gemm_fused<1024, 512, 4, false, false, false, true>
      <<<256, 512, 0, stream>>>(bufF, Wht, bh, nullptr, nullptr, bufP, permb, ids);
  // L5: 512 -> 512, gelu
  gemm_fused<512, 512, 4, false, true, false, false>
      <<<256, 512, 0, stream>>>(bufP, Wd1t, bd1, nullptr, nullptr, bufQ, nullptr, nullptr);
  // L6: 512 -> 512, fp32 out (w)
  gemm_fused<512, 512, 4, false, false, true, false>
      <<<256, 512, 0, stream>>>(bufQ, Wd2t, bd2, nullptr, nullptr, w6, nullptr, nullptr);

  // conv stack + residual + per-id scale
  conv_kernel<<<8192, 256, 0, stream>>>(w6, cw1, cb1, cw2p, cb2, cw3, cb3,
                                        scales, ids, out);
}

// Round 7
// 847.681 us; speedup vs baseline: 1.4530x; 1.4530x over previous
//
#include <hip/hip_runtime.h>
#include <math.h>

// ---------------------------------------------------------------------------
// MultiTopologySurrogate: fused bf16-MFMA pipeline for MI355X (gfx950)
// ---------------------------------------------------------------------------

using bf16x8 = __attribute__((ext_vector_type(8))) short;
using f32x4  = __attribute__((ext_vector_type(4))) float;

static __device__ __forceinline__ short f2bf(float f) {
  union { float f; unsigned u; } v; v.f = f;
  unsigned r = v.u + 0x7fffu + ((v.u >> 16) & 1u);  // RNE
  return (short)(r >> 16);
}
static __device__ __forceinline__ float bf2f(short s) {
  union { unsigned u; float f; } v; v.u = ((unsigned)(unsigned short)s) << 16;
  return v.f;
}
// tanh-form gelu: max |diff| vs exact ~3e-3, well under threshold.
static __device__ __forceinline__ float gelu_fast(float x) {
  float u = 0.7978845608f * x * (1.f + 0.044715f * x * x);
  u = fminf(fmaxf(u, -15.f), 15.f);          // avoid exp overflow -> NaN
  float e = __expf(-2.f * u);
  float t = __fdividef(1.f - e, 1.f + e);    // tanh(u)
  return 0.5f * x * (1.f + t);
}

// --------------------------- bucket-by-id kernels ---------------------------
__global__ void k_zero(int* c) { if (threadIdx.x < 8) c[threadIdx.x] = 0; }

__global__ void k_count(const int* __restrict__ ids, int* __restrict__ cnt) {
  int i = blockIdx.x * 256 + threadIdx.x;
  if (i < 8192) atomicAdd(&cnt[ids[i]], 1);
}

__global__ void k_assign(const int* __restrict__ ids, const int* __restrict__ cnt,
                         int* __restrict__ cur, int* __restrict__ perm) {
  int i = blockIdx.x * 256 + threadIdx.x;
  if (i >= 8192) return;
  int t = ids[i];
  int base = 0;
  if (t > 0) base += cnt[0];
  if (t > 1) base += cnt[1];
  int pos = base + atomicAdd(&cur[t], 1);
  perm[pos] = i;
}

// ---------------- weight prep (fp32 -> bf16 B^T layout) ---------------------
// padded variant (W1 only: K=38 -> Kpad=64), index over output
__global__ void prep_wt_pad(const float* __restrict__ W, short* __restrict__ Wt,
                            int K, int N, int Kpad) {
  int i = blockIdx.x * 256 + threadIdx.x;
  if (i >= N * Kpad) return;
  int n = i / Kpad, k = i - n * Kpad;
  float v = (k < K) ? W[(size_t)k * N + n] : 0.f;
  Wt[i] = f2bf(v);
}

// coalesced-read variant (Kpad==K): read W contiguous, scatter-store Wt[n][k]
__global__ void prep_wt_t(const float* __restrict__ W, short* __restrict__ Wt,
                          int K, int N, int batch) {
  long i = (long)blockIdx.x * 256 + threadIdx.x;
  long per = (long)K * N;
  if (i >= per * batch) return;
  int t = (int)(i / per);
  long j = i - (long)t * per;
  int k = (int)(j / N);
  int n = (int)(j - (long)k * N);
  Wt[(long)t * per + (long)n * K + k] = f2bf(W[i]);
}

// cw2p[c_out][tap*32 + c_in] = cw2[c_out][c_in][tap]   (K=160 flattened)
__global__ void prep_cw2(const float* __restrict__ cw2, short* __restrict__ cw2p) {
  int i = blockIdx.x * 256 + threadIdx.x;
  if (i >= 32 * 160) return;
  int co = i / 160, j = i - co * 160;
  int tap = j >> 5, ci = j & 31;
  cw2p[i] = f2bf(cw2[(co * 32 + ci) * 5 + tap]);
}

// cw3p[16][128]: row 0 = cw3 flattened [tap*32+c], rows 1-15 zero, tap 3 zero
__global__ void prep_cw3(const float* __restrict__ cw3, short* __restrict__ cw3p) {
  int i = blockIdx.x * 256 + threadIdx.x;
  if (i >= 16 * 128) return;
  int m = i >> 7, j = i & 127;
  int kk = j >> 5, c = j & 31;
  float v = (m == 0 && kk < 3) ? cw3[c * 3 + kk] : 0.f;
  cw3p[i] = f2bf(v);
}

// --------------------------- input featurization ----------------------------
__global__ void build_x(const float* __restrict__ params, const float* __restrict__ emb,
                        const int* __restrict__ ids, short* __restrict__ xb) {
  int i = blockIdx.x * 256 + threadIdx.x;
  if (i >= 8192 * 64) return;
  int row = i >> 6, c = i & 63;
  float v;
  const float lo[6] = {1e-05f, 4.7e-05f, 2.0f, 5.0f, 50000.0f, 0.2f};
  const float hi[6] = {0.00047f, 0.001f, 100.0f, 24.0f, 500000.0f, 0.8f};
  const int lg[6] = {1, 1, 0, 0, 1, 0};
  if (c < 6) {
    float pv = params[row * 6 + c];
    if (lg[c]) v = (logf(pv) - logf(lo[c])) / (logf(hi[c]) - logf(lo[c]));
    else       v = (pv - lo[c]) / (hi[c] - lo[c]);
    v = fminf(fmaxf(v, 0.f), 1.f);
  } else if (c < 38) {
    v = emb[ids[row] * 32 + (c - 6)];
  } else v = 0.f;
  xb[i] = f2bf(v);
}

// --------------------------- generic fused GEMM (16 rows/block) -------------
// out[b][n] = (opt LN)(opt GELU)( A[b][:] @ W + bias );  grid = B/16 = 512
// MFMA 16x16x32: A lane l -> A[l&15][(l>>4)*8+j]; B lane l -> B[(l>>4)*8+j][l&15];
// D: col=l&15, row=(l>>4)*4+reg.
template<int K, int N, int NTW, bool DO_LN, bool DO_GELU, bool OUT_F32, bool GATHER>
__global__ __launch_bounds__(512, 4) void gemm16(
    const short* __restrict__ A, const short* __restrict__ Wt,
    const float* __restrict__ bias, const float* __restrict__ gam,
    const float* __restrict__ bet, void* __restrict__ outp,
    const int* __restrict__ perm, const int* __restrict__ ids) {
  const int tid = threadIdx.x;
  const int wave = tid >> 6;
  const int lane = tid & 63;
  const int g16 = lane >> 4;
  const int l16 = lane & 15;
  const int rowBase = blockIdx.x * 16;
  const int colBase = wave * (NTW * 16);

  __shared__ int sPerm[16];
  __shared__ int sId[16];
  __shared__ int sFlag[3];
  __shared__ float sPart[16][8][2];
  __shared__ float sStat[16][2];

  if (GATHER) {
    if (tid < 16) {
      int pr = perm[rowBase + tid];
      sPerm[tid] = pr;
      sId[tid] = ids[pr];
    }
    __syncthreads();
    if (tid < 3) {
      int f = 0;
      for (int i = 0; i < 16; ++i) f |= (sId[i] == tid) ? 1 : 0;
      sFlag[tid] = f;
    }
    __syncthreads();
  }

  const int arow = GATHER ? sPerm[l16] : (rowBase + l16);
  const size_t aoff = (size_t)arow * K + g16 * 8;
  size_t boff[NTW];
#pragma unroll
  for (int nt = 0; nt < NTW; ++nt) {
    int n = colBase + nt * 16 + l16;
    boff[nt] = (size_t)n * K + g16 * 8;
  }

  const f32x4 vzero = {0.f, 0.f, 0.f, 0.f};
  const int TMAX = GATHER ? 3 : 1;
  for (int t = 0; t < TMAX; ++t) {
    if (GATHER && !sFlag[t]) continue;
    const short* Wtt = Wt + (GATHER ? (size_t)t * N * K : 0);
    const float* bt = bias + (GATHER ? t * N : 0);

    f32x4 acc[NTW];
#pragma unroll
    for (int nt = 0; nt < NTW; ++nt) acc[nt] = vzero;

    for (int kk = 0; kk < K / 32; ++kk) {
      bf16x8 a0 = *(const bf16x8*)(A + aoff + kk * 32);
#pragma unroll
      for (int nt = 0; nt < NTW; ++nt) {
        bf16x8 bq = *(const bf16x8*)(Wtt + boff[nt] + kk * 32);
        acc[nt] = __builtin_amdgcn_mfma_f32_16x16x32_bf16(a0, bq, acc[nt], 0, 0, 0);
      }
    }

    // bias add (precedes LN stats)
#pragma unroll
    for (int nt = 0; nt < NTW; ++nt) {
      float bv = bt[colBase + nt * 16 + l16];
#pragma unroll
      for (int r = 0; r < 4; ++r) acc[nt][r] += bv;
    }

    if (DO_LN) {
#pragma unroll
      for (int r = 0; r < 4; ++r) {
        float s = 0.f, q = 0.f;
#pragma unroll
        for (int nt = 0; nt < NTW; ++nt) {
          float x = acc[nt][r];
          s += x; q += x * x;
        }
#pragma unroll
        for (int m = 1; m < 16; m <<= 1) {
          s += __shfl_xor(s, m);
          q += __shfl_xor(q, m);
        }
        if (l16 == 0) {
          int row = g16 * 4 + r;
          sPart[row][wave][0] = s;
          sPart[row][wave][1] = q;
        }
      }
      __syncthreads();
      if (tid < 16) {
        float s = 0.f, q = 0.f;
#pragma unroll
        for (int w = 0; w < 8; ++w) { s += sPart[tid][w][0]; q += sPart[tid][w][1]; }
        float mean = s / (float)N;
        float var = q / (float)N - mean * mean;
        sStat[tid][0] = mean;
        sStat[tid][1] = rsqrtf(var + 1e-5f);
      }
      __syncthreads();
    }

#pragma unroll
    for (int nt = 0; nt < NTW; ++nt) {
      int col = colBase + nt * 16 + l16;
      float gv = DO_LN ? gam[col] : 0.f;
      float bev = DO_LN ? bet[col] : 0.f;
#pragma unroll
      for (int r = 0; r < 4; ++r) {
        int row = g16 * 4 + r;
        if (GATHER && sId[row] != t) continue;
        float x = acc[nt][r];
        if (DO_LN) x = (x - sStat[row][0]) * sStat[row][1] * gv + bev;
        if (DO_GELU) x = gelu_fast(x);
        size_t grow = GATHER ? (size_t)sPerm[row] : (size_t)(rowBase + row);
        if (OUT_F32) ((float*)outp)[grow * N + col] = x;
        else ((short*)outp)[grow * N + col] = f2bf(x);
      }
    }
  }
}

// --------------------------- conv stack ------------------------------------
// One block per batch row, 512 threads (8 waves x 64 positions each).
// conv1 (1->32,k7) VALU; conv2 (32->32,k5) implicit MFMA GEMM (K=160);
// conv3 (32->1,k3) implicit MFMA GEMM (K=96, A row 0 only).
// y LDS: [row][c] bf16, row stride 64B, XOR swizzle ((r&3)<<4) on byte addr.
// y1 rows = pos+2 (pads 0,1,514,515); y2 reuses buffer, rows = pos+1 (pads 0,513).
__global__ __launch_bounds__(512, 4) void conv_kernel(
    const float* __restrict__ w6, const float* __restrict__ cw1,
    const float* __restrict__ cb1, const short* __restrict__ cw2p,
    const float* __restrict__ cb2, const short* __restrict__ cw3p,
    const float* __restrict__ cb3, const float* __restrict__ scales,
    const int* __restrict__ ids, float* __restrict__ out) {
  const int b = blockIdx.x;
  const int tid = threadIdx.x;
  const int wave = tid >> 6, lane = tid & 63;
  const int g16 = lane >> 4, l16 = lane & 15;
  const int waveBase = wave * 64;

  __shared__ float sw[520];                 // w padded by 3 each side (idx t+3)
  __shared__ __align__(16) short y[516 * 32];
  __shared__ float scw1[224];
  __shared__ float scb1[32];
  __shared__ float r3s[512];

  const float* wr = w6 + (size_t)b * 512;
  for (int i = tid; i < 518; i += 512) {
    int t = i - 3;
    sw[i] = (t >= 0 && t < 512) ? wr[t] : 0.f;
  }
  if (tid < 224) scw1[tid] = cw1[tid];
  if (tid >= 256 && tid < 288) scb1[tid - 256] = cb1[tid - 256];
  if (tid >= 384 && tid < 512) {  // zero y1 pad rows 0,1,514,515
    int i = tid - 384;
    int rr = i >> 5;
    int r = (rr < 2) ? rr : (512 + rr);
    int c = i & 31;
    int byte = (r << 6) + ((c << 1) ^ ((r & 3) << 4));
    *(short*)((char*)y + byte) = 0;
  }
  __syncthreads();

  // conv1 + gelu -> y1[t+2][c]
  for (int it = 0; it < 32; ++it) {
    int idx = tid + it * 512;
    int c = idx & 31, t = idx >> 5;
    float s = scb1[c];
#pragma unroll
    for (int k = 0; k < 7; ++k) s += scw1[c * 7 + k] * sw[t + k];
    s = gelu_fast(s);
    int r = t + 2;
    int byte = (r << 6) + ((c << 1) ^ ((r & 3) << 4));
    *(short*)((char*)y + byte) = f2bf(s);
  }
  __syncthreads();

  // conv2 via MFMA: per wave 64 positions (4 nt tiles), M=32 (2 mt)
  const f32x4 vzero = {0.f, 0.f, 0.f, 0.f};
  f32x4 acc[2][4];
#pragma unroll
  for (int mt = 0; mt < 2; ++mt)
#pragma unroll
    for (int nt = 0; nt < 4; ++nt) acc[mt][nt] = vzero;

#pragma unroll
  for (int kk = 0; kk < 5; ++kk) {
    bf16x8 a0 = *(const bf16x8*)(cw2p + (l16) * 160 + kk * 32 + g16 * 8);
    bf16x8 a1 = *(const bf16x8*)(cw2p + (16 + l16) * 160 + kk * 32 + g16 * 8);
#pragma unroll
    for (int nt = 0; nt < 4; ++nt) {
      int r = waveBase + nt * 16 + l16 + kk;  // y1 row = pos + (kk-2) + 2
      int byte = (r << 6) + ((g16 << 4) ^ ((r & 3) << 4));
      bf16x8 bq = *(const bf16x8*)((char*)y + byte);
      acc[0][nt] = __builtin_amdgcn_mfma_f32_16x16x32_bf16(a0, bq, acc[0][nt], 0, 0, 0);
      acc[1][nt] = __builtin_amdgcn_mfma_f32_16x16x32_bf16(a1, bq, acc[1][nt], 0, 0, 0);
    }
  }
  __syncthreads();  // all y1 reads complete before overwrite

  if (tid < 64) {  // zero y2 pad rows 0, 513
    int r = (tid < 32) ? 0 : 513;
    int c = tid & 31;
    int byte = (r << 6) + ((c << 1) ^ ((r & 3) << 4));
    *(short*)((char*)y + byte) = 0;
  }
  // y2[pos+1][c_out] = gelu(acc + cb2)
#pragma unroll
  for (int mt = 0; mt < 2; ++mt)
#pragma unroll
    for (int nt = 0; nt < 4; ++nt) {
      int t = waveBase + nt * 16 + l16;
      int c0 = mt * 16 + g16 * 4;
      union { short s[4]; unsigned u[2]; } pk;
#pragma unroll
      for (int r = 0; r < 4; ++r) {
        float x = acc[mt][nt][r] + cb2[c0 + r];
        pk.s[r] = f2bf(gelu_fast(x));
      }
      int r2 = t + 1;
      int byte = (r2 << 6) + ((c0 << 1) ^ ((r2 & 3) << 4));
      *(unsigned*)((char*)y + byte) = pk.u[0];
      *(unsigned*)((char*)y + byte + 4) = pk.u[1];
    }
  __syncthreads();

  // conv3 via MFMA: A = cw3p (row 0 only), K=96 (3 taps x 32 ch)
  bf16x8 a3[3];
#pragma unroll
  for (int kk = 0; kk < 3; ++kk)
    a3[kk] = *(const bf16x8*)(cw3p + l16 * 128 + kk * 32 + g16 * 8);

  f32x4 acc3[4];
#pragma unroll
  for (int nt = 0; nt < 4; ++nt) acc3[nt] = vzero;
#pragma unroll
  for (int kk = 0; kk < 3; ++kk) {
#pragma unroll
    for (int nt = 0; nt < 4; ++nt) {
      // B element for output pos t=waveBase+nt*16+l16, tap kk: y2 row t+kk
      int r = waveBase + nt * 16 + l16 + kk;
      int byte = (r << 6) + ((g16 << 4) ^ ((r & 3) << 4));
      bf16x8 bq = *(const bf16x8*)((char*)y + byte);
      acc3[nt] = __builtin_amdgcn_mfma_f32_16x16x32_bf16(a3[kk], bq, acc3[nt], 0, 0, 0);
    }
  }
  // D row 0 (lanes 0-15, reg 0) holds conv3[t0 + col]
  if (g16 == 0) {
#pragma unroll
    for (int nt = 0; nt < 4; ++nt) r3s[waveBase + nt * 16 + l16] = acc3[nt][0];
  }
  __syncthreads();

  const float scale = scales[ids[b]];
  const float c3b = cb3[0];
  {
    int t = tid;
    out[(size_t)b * 512 + t] = (sw[t + 3] + r3s[t] + c3b) * scale;
  }
}

// --------------------------- launch ----------------------------------------
extern "C" void kernel_launch(void* const* d_in, const int* in_sizes, int n_in,
                              void* d_out, int out_size, void* d_ws, size_t ws_size,
                              hipStream_t stream) {
  (void)in_sizes; (void)n_in; (void)out_size; (void)ws_size;
  const float* params = (const float*)d_in[0];
  const float* emb    = (const float*)d_in[1];
  const float* W1  = (const float*)d_in[2];
  const float* b1  = (const float*)d_in[3];
  const float* g1  = (const float*)d_in[4];
  const float* be1 = (const float*)d_in[5];
  const float* W2  = (const float*)d_in[6];
  const float* b2  = (const float*)d_in[7];
  const float* g2  = (const float*)d_in[8];
  const float* be2 = (const float*)d_in[9];
  const float* W3  = (const float*)d_in[10];
  const float* b3  = (const float*)d_in[11];
  const float* g3  = (const float*)d_in[12];
  const float* be3 = (const float*)d_in[13];
  const float* Wh  = (const float*)d_in[14];
  const float* bh  = (const float*)d_in[15];
  const float* Wd1 = (const float*)d_in[16];
  const float* bd1 = (const float*)d_in[17];
  const float* Wd2 = (const float*)d_in[18];
  const float* bd2 = (const float*)d_in[19];
  const float* cw1 = (const float*)d_in[20];
  const float* cb1 = (const float*)d_in[21];
  const float* cw2 = (const float*)d_in[22];
  const float* cb2 = (const float*)d_in[23];
  const float* cw3 = (const float*)d_in[24];
  const float* cb3 = (const float*)d_in[25];
  const float* scales = (const float*)d_in[26];
  const int* ids = (const int*)d_in[27];
  float* out = (float*)d_out;

  char* ws = (char*)d_ws;
  size_t off = 0;
  auto alloc = [&](size_t bytes) {
    size_t r = off;
    off += (bytes + 255) & ~(size_t)255;
    return r;
  };
  short* W1t  = (short*)(ws + alloc((size_t)512 * 64 * 2));
  short* W2t  = (short*)(ws + alloc((size_t)512 * 512 * 2));
  short* W3t  = (short*)(ws + alloc((size_t)1024 * 512 * 2));
  short* Wht  = (short*)(ws + alloc((size_t)3 * 512 * 1024 * 2));
  short* Wd1t = (short*)(ws + alloc((size_t)512 * 512 * 2));
  short* Wd2t = (short*)(ws + alloc((size_t)512 * 512 * 2));
  short* cw2p = (short*)(ws + alloc((size_t)32 * 160 * 2));
  short* cw3p = (short*)(ws + alloc((size_t)16 * 128 * 2));
  short* xb   = (short*)(ws + alloc((size_t)8192 * 64 * 2));
  short* bufP = (short*)(ws + alloc((size_t)8192 * 512 * 2));
  short* bufQ = (short*)(ws + alloc((size_t)8192 * 512 * 2));
  short* bufF = (short*)(ws + alloc((size_t)8192 * 1024 * 2));  // feat, later w6 (fp32)
  int*   cntb = (int*)(ws + alloc(64));
  int*   permb = (int*)(ws + alloc((size_t)8192 * 4));
  float* w6 = (float*)bufF;  // feat is dead once GEMM4 completes

  auto gp = [](long tot) { return (int)((tot + 255) / 256); };

  // bucket rows by topology id
  k_zero<<<1, 64, 0, stream>>>(cntb);
  k_count<<<32, 256, 0, stream>>>(ids, cntb);
  k_assign<<<32, 256, 0, stream>>>(ids, cntb, cntb + 4, permb);

  // weight prep (fp32 -> bf16 B^T layout)
  prep_wt_pad<<<gp(512 * 64), 256, 0, stream>>>(W1, W1t, 38, 512, 64);
  prep_wt_t<<<gp(512 * 512), 256, 0, stream>>>(W2, W2t, 512, 512, 1);
  prep_wt_t<<<gp(1024 * 512), 256, 0, stream>>>(W3, W3t, 512, 1024, 1);
  prep_wt_t<<<gp(3L * 512 * 1024), 256, 0, stream>>>(Wh, Wht, 1024, 512, 3);
  prep_wt_t<<<gp(512 * 512), 256, 0, stream>>>(Wd1, Wd1t, 512, 512, 1);
  prep_wt_t<<<gp(512 * 512), 256, 0, stream>>>(Wd2, Wd2t, 512, 512, 1);
  prep_cw2<<<gp(32 * 160), 256, 0, stream>>>(cw2, cw2p);
  prep_cw3<<<gp(16 * 128), 256, 0, stream>>>(cw3, cw3p);

  build_x<<<gp(8192L * 64), 256, 0, stream>>>(params, emb, ids, xb);

  // L1: x(64) -> 512, LN+gelu
  gemm16<64, 512, 4, true, true, false, false>
      <<<512, 512, 0, stream>>>(xb, W1t, b1, g1, be1, bufP, nullptr, nullptr);
  // L2: 512 -> 512, LN+gelu
  gemm16<512, 512, 4, true, true, false, false>
      <<<512, 512, 0, stream>>>(bufP, W2t, b2, g2, be2, bufQ, nullptr, nullptr);
  // L3: 512 -> 1024, LN+gelu -> feat
  gemm16<512, 1024, 8, true, true, false, false>
      <<<512, 512, 0, stream>>>(bufQ, W3t, b3, g3, be3, bufF, nullptr, nullptr);
  // L4: gathered per-topology 1024 -> 512 (+bh), bucketed rows
  gemm16<1024, 512, 4, false, false, false, true>
      <<<512, 512, 0, stream>>>(bufF, Wht, bh, nullptr, nullptr, bufP, permb, ids);
  // L5: 512 -> 512, gelu
  gemm16<512, 512, 4, false, true, false, false>
      <<<512, 512, 0, stream>>>(bufP, Wd1t, bd1, nullptr, nullptr, bufQ, nullptr, nullptr);
  // L6: 512 -> 512, fp32 out (w)
  gemm16<512, 512, 4, false, false, true, false>
      <<<512, 512, 0, stream>>>(bufQ, Wd2t, bd2, nullptr, nullptr, w6, nullptr, nullptr);

  // conv stack + residual + per-id scale
  conv_kernel<<<8192, 512, 0, stream>>>(w6, cw1, cb1, cw2p, cb2, cw3p, cb3,
                                        scales, ids, out);
}

// Round 10
// 712.754 us; speedup vs baseline: 1.7280x; 1.1893x over previous
//
#include <hip/hip_runtime.h>
#include <math.h>

// ---------------------------------------------------------------------------
// MultiTopologySurrogate: fused bf16-MFMA pipeline for MI355X (gfx950)
// ---------------------------------------------------------------------------

using bf16x8 = __attribute__((ext_vector_type(8))) short;
using f32x4  = __attribute__((ext_vector_type(4))) float;

static __device__ __forceinline__ short f2bf(float f) {
  union { float f; unsigned u; } v; v.f = f;
  unsigned r = v.u + 0x7fffu + ((v.u >> 16) & 1u);  // RNE
  return (short)(r >> 16);
}
// pack two f32 -> two bf16 (RNE) in one instruction
static __device__ __forceinline__ unsigned cvt_pk_bf16(float lo, float hi) {
  unsigned r;
  asm("v_cvt_pk_bf16_f32 %0, %1, %2" : "=v"(r) : "v"(lo), "v"(hi));
  return r;
}
// tanh-form gelu, algebraically reduced: 0.5x(1+tanh(u)) = x/(1+exp(-2u))
// exp via exp2: z = -2*log2(e)*0.7978845608*x*(1+0.044715*x^2) = x*(c1+c3*x^2)
// overflow-safe: z->+inf => e=inf => x*rcp(inf)=+-0 (gelu(-big)=0), z->-inf => e=0 => x.
static __device__ __forceinline__ float gelu_cheap(float x) {
  const float c1 = -2.3022077f;
  const float c3 = -0.10294858f;
  float xx = x * x;
  float z = x * fmaf(c3, xx, c1);
  float e = __builtin_amdgcn_exp2f(z);
  float r = __builtin_amdgcn_rcpf(1.f + e);
  return x * r;
}

// --------------------------- bucket-by-id kernels ---------------------------
__global__ void k_zero(int* c) { if (threadIdx.x < 8) c[threadIdx.x] = 0; }

__global__ void k_count(const int* __restrict__ ids, int* __restrict__ cnt) {
  int i = blockIdx.x * 256 + threadIdx.x;
  if (i < 8192) atomicAdd(&cnt[ids[i]], 1);
}

__global__ void k_assign(const int* __restrict__ ids, const int* __restrict__ cnt,
                         int* __restrict__ cur, int* __restrict__ perm) {
  int i = blockIdx.x * 256 + threadIdx.x;
  if (i >= 8192) return;
  int t = ids[i];
  int base = 0;
  if (t > 0) base += cnt[0];
  if (t > 1) base += cnt[1];
  int pos = base + atomicAdd(&cur[t], 1);
  perm[pos] = i;
}

// ---------------- weight prep (fp32 -> bf16 B^T layout) ---------------------
// padded variant (W1 only: K=38 -> Kpad=64), index over output
__global__ void prep_wt_pad(const float* __restrict__ W, short* __restrict__ Wt,
                            int K, int N, int Kpad) {
  int i = blockIdx.x * 256 + threadIdx.x;
  if (i >= N * Kpad) return;
  int n = i / Kpad, k = i - n * Kpad;
  float v = (k < K) ? W[(size_t)k * N + n] : 0.f;
  Wt[i] = f2bf(v);
}

// tiled transpose: W[K][N] fp32 -> Wt[N][K] bf16, coalesced read AND write.
// grid.x = (N/32)*(K/32), grid.y = batch index
__global__ void prep_wt_tile(const float* __restrict__ W, short* __restrict__ Wt,
                             int K, int N) {
  int ntk = K >> 5;
  int tile = blockIdx.x;
  int nb = tile / ntk, kb = tile - nb * ntk;
  const float* Wb = W + (size_t)blockIdx.y * K * N;
  short* Wtb = Wt + (size_t)blockIdx.y * K * N;
  __shared__ float t[32][33];
  int j = threadIdx.x & 31, i0 = threadIdx.x >> 5;
#pragma unroll
  for (int q = 0; q < 4; ++q) {
    int i = i0 + q * 8;
    t[i][j] = Wb[(size_t)(kb * 32 + i) * N + nb * 32 + j];
  }
  __syncthreads();
#pragma unroll
  for (int q = 0; q < 4; ++q) {
    int i = i0 + q * 8;
    Wtb[(size_t)(nb * 32 + i) * K + kb * 32 + j] = f2bf(t[j][i]);
  }
}

// cw2p[c_out][tap*32 + c_in] = cw2[c_out][c_in][tap]   (K=160 flattened)
__global__ void prep_cw2(const float* __restrict__ cw2, short* __restrict__ cw2p) {
  int i = blockIdx.x * 256 + threadIdx.x;
  if (i >= 32 * 160) return;
  int co = i / 160, j = i - co * 160;
  int tap = j >> 5, ci = j & 31;
  cw2p[i] = f2bf(cw2[(co * 32 + ci) * 5 + tap]);
}

// cw3p[16][128]: row 0 = cw3 flattened [tap*32+c], rows 1-15 zero, tap 3 zero
__global__ void prep_cw3(const float* __restrict__ cw3, short* __restrict__ cw3p) {
  int i = blockIdx.x * 256 + threadIdx.x;
  if (i >= 16 * 128) return;
  int m = i >> 7, j = i & 127;
  int kk = j >> 5, c = j & 31;
  float v = (m == 0 && kk < 3) ? cw3[c * 3 + kk] : 0.f;
  cw3p[i] = f2bf(v);
}

// --------------------------- input featurization ----------------------------
__global__ void build_x(const float* __restrict__ params, const float* __restrict__ emb,
                        const int* __restrict__ ids, short* __restrict__ xb) {
  int i = blockIdx.x * 256 + threadIdx.x;
  if (i >= 8192 * 64) return;
  int row = i >> 6, c = i & 63;
  float v;
  const float lo[6] = {1e-05f, 4.7e-05f, 2.0f, 5.0f, 50000.0f, 0.2f};
  const float hi[6] = {0.00047f, 0.001f, 100.0f, 24.0f, 500000.0f, 0.8f};
  const int lg[6] = {1, 1, 0, 0, 1, 0};
  if (c < 6) {
    float pv = params[row * 6 + c];
    if (lg[c]) v = (logf(pv) - logf(lo[c])) / (logf(hi[c]) - logf(lo[c]));
    else       v = (pv - lo[c]) / (hi[c] - lo[c]);
    v = fminf(fmaxf(v, 0.f), 1.f);
  } else if (c < 38) {
    v = emb[ids[row] * 32 + (c - 6)];
  } else v = 0.f;
  xb[i] = f2bf(v);
}

// --------------------------- generic fused GEMM (16 rows/block) -------------
// out[b][n] = (opt LN)(opt GELU)( A[b][:] @ W + bias );  grid = B/16 = 512
// MFMA 16x16x32: A lane l -> A[l&15][(l>>4)*8+j]; B lane l -> B[(l>>4)*8+j][l&15];
// D: col=l&15, row=(l>>4)*4+reg.
template<int K, int N, int NTW, bool DO_LN, bool DO_GELU, bool OUT_F32, bool GATHER>
__global__ __launch_bounds__(512, 4) void gemm16(
    const short* __restrict__ A, const short* __restrict__ Wt,
    const float* __restrict__ bias, const float* __restrict__ gam,
    const float* __restrict__ bet, void* __restrict__ outp,
    const int* __restrict__ perm, const int* __restrict__ ids) {
  const int tid = threadIdx.x;
  const int wave = tid >> 6;
  const int lane = tid & 63;
  const int g16 = lane >> 4;
  const int l16 = lane & 15;
  const int rowBase = blockIdx.x * 16;
  const int colBase = wave * (NTW * 16);

  __shared__ int sPerm[16];
  __shared__ int sId[16];
  __shared__ int sFlag[3];
  __shared__ float sPart[16][8][2];
  __shared__ float sStat[16][2];

  if (GATHER) {
    if (tid < 16) {
      int pr = perm[rowBase + tid];
      sPerm[tid] = pr;
      sId[tid] = ids[pr];
    }
    __syncthreads();
    if (tid < 3) {
      int f = 0;
      for (int i = 0; i < 16; ++i) f |= (sId[i] == tid) ? 1 : 0;
      sFlag[tid] = f;
    }
    __syncthreads();
  }

  const int arow = GATHER ? sPerm[l16] : (rowBase + l16);
  const size_t aoff = (size_t)arow * K + g16 * 8;
  size_t boff[NTW];
#pragma unroll
  for (int nt = 0; nt < NTW; ++nt) {
    int n = colBase + nt * 16 + l16;
    boff[nt] = (size_t)n * K + g16 * 8;
  }

  const f32x4 vzero = {0.f, 0.f, 0.f, 0.f};
  const int TMAX = GATHER ? 3 : 1;
  for (int t = 0; t < TMAX; ++t) {
    if (GATHER && !sFlag[t]) continue;
    const short* Wtt = Wt + (GATHER ? (size_t)t * N * K : 0);
    const float* bt = bias + (GATHER ? t * N : 0);

    f32x4 acc[NTW];
#pragma unroll
    for (int nt = 0; nt < NTW; ++nt) acc[nt] = vzero;

    for (int kk = 0; kk < K / 32; ++kk) {
      bf16x8 a0 = *(const bf16x8*)(A + aoff + kk * 32);
#pragma unroll
      for (int nt = 0; nt < NTW; ++nt) {
        bf16x8 bq = *(const bf16x8*)(Wtt + boff[nt] + kk * 32);
        acc[nt] = __builtin_amdgcn_mfma_f32_16x16x32_bf16(a0, bq, acc[nt], 0, 0, 0);
      }
    }

    // bias add (precedes LN stats)
#pragma unroll
    for (int nt = 0; nt < NTW; ++nt) {
      float bv = bt[colBase + nt * 16 + l16];
#pragma unroll
      for (int r = 0; r < 4; ++r) acc[nt][r] += bv;
    }

    if (DO_LN) {
#pragma unroll
      for (int r = 0; r < 4; ++r) {
        float s = 0.f, q = 0.f;
#pragma unroll
        for (int nt = 0; nt < NTW; ++nt) {
          float x = acc[nt][r];
          s += x; q += x * x;
        }
#pragma unroll
        for (int m = 1; m < 16; m <<= 1) {
          s += __shfl_xor(s, m);
          q += __shfl_xor(q, m);
        }
        if (l16 == 0) {
          int row = g16 * 4 + r;
          sPart[row][wave][0] = s;
          sPart[row][wave][1] = q;
        }
      }
      __syncthreads();
      if (tid < 16) {
        float s = 0.f, q = 0.f;
#pragma unroll
        for (int w = 0; w < 8; ++w) { s += sPart[tid][w][0]; q += sPart[tid][w][1]; }
        float mean = s / (float)N;
        float var = q / (float)N - mean * mean;
        sStat[tid][0] = mean;
        sStat[tid][1] = rsqrtf(var + 1e-5f);
      }
      __syncthreads();
    }

#pragma unroll
    for (int nt = 0; nt < NTW; ++nt) {
      int col = colBase + nt * 16 + l16;
      float gv = DO_LN ? gam[col] : 0.f;
      float bev = DO_LN ? bet[col] : 0.f;
#pragma unroll
      for (int r = 0; r < 4; ++r) {
        int row = g16 * 4 + r;
        if (GATHER && sId[row] != t) continue;
        float x = acc[nt][r];
        if (DO_LN) x = (x - sStat[row][0]) * sStat[row][1] * gv + bev;
        if (DO_GELU) x = gelu_cheap(x);
        size_t grow = GATHER ? (size_t)sPerm[row] : (size_t)(rowBase + row);
        if (OUT_F32) ((float*)outp)[grow * N + col] = x;
        else ((short*)outp)[grow * N + col] = f2bf(x);
      }
    }
  }
}

// --------------------------- conv stack ------------------------------------
// One block per batch row, 512 threads.
// conv1 (1->32,k7): thread owns 4 channels x 1 position; 28 weights in VGPRs,
//   7 lane-broadcast ds_read_b32 of sw, 28 FMA, 1 ds_write_b64. 8 iterations.
// conv2 (32->32,k5): implicit MFMA GEMM (K=160).
// conv3 (32->1,k3): implicit MFMA GEMM (K=96, A row 0 only).
// y LDS: [row][c] bf16, row stride 64B, XOR swizzle ((r>>1)&3)<<4 on byte addr
//   (even rows rotate all four 16B slots -> b128 reads hit their bank floor).
// y1 rows = pos+2 (pads 0,1,514,515); y2 reuses buffer, rows = pos+1 (pads 0,513).
__global__ __launch_bounds__(512, 4) void conv_kernel(
    const float* __restrict__ w6, const float* __restrict__ cw1,
    const float* __restrict__ cb1, const short* __restrict__ cw2p,
    const float* __restrict__ cb2, const short* __restrict__ cw3p,
    const float* __restrict__ cb3, const float* __restrict__ scales,
    const int* __restrict__ ids, float* __restrict__ out) {
  const int b = blockIdx.x;
  const int tid = threadIdx.x;
  const int wave = tid >> 6, lane = tid & 63;
  const int g16 = lane >> 4, l16 = lane & 15;
  const int waveBase = wave * 64;

  __shared__ float sw[520];                 // sw[i] = w[i-3], i in [0,519)
  __shared__ __align__(16) short y[516 * 32];
  __shared__ float r3s[512];

  // conv1 constants: c0 = (tid&7)*4 channels; 28 weights + 4 biases in regs
  const int c0 = (tid & 7) * 4;
  float w28[28];
  {
    const float4* wp = (const float4*)(cw1 + c0 * 7);  // 28 floats, 16B-aligned
#pragma unroll
    for (int m = 0; m < 7; ++m) {
      float4 v = wp[m];
      w28[m * 4 + 0] = v.x; w28[m * 4 + 1] = v.y;
      w28[m * 4 + 2] = v.z; w28[m * 4 + 3] = v.w;
    }
  }
  const float4 bias1 = *(const float4*)(cb1 + c0);

  const float* wr = w6 + (size_t)b * 512;
  for (int i = tid; i < 519; i += 512) {
    int t = i - 3;
    sw[i] = (t >= 0 && t < 512) ? wr[t] : 0.f;
  }
  if (tid >= 384 && tid < 512) {  // zero y1 pad rows 0,1,514,515
    int i = tid - 384;
    int rr = i >> 5;
    int r = (rr < 2) ? rr : (512 + rr);
    int c = i & 31;
    int byte = (r << 6) + ((c << 1) ^ (((r >> 1) & 3) << 4));
    *(short*)((char*)y + byte) = 0;
  }
  __syncthreads();

  // conv1 + gelu -> y1[t+2][c0..c0+3]
  const float b1v[4] = {bias1.x, bias1.y, bias1.z, bias1.w};
#pragma unroll
  for (int it = 0; it < 8; ++it) {
    int t = (tid >> 3) + it * 64;          // 0..511
    float swv[7];
#pragma unroll
    for (int k = 0; k < 7; ++k) swv[k] = sw[t + k];   // lane-broadcast reads
    float o[4];
#pragma unroll
    for (int q = 0; q < 4; ++q) {
      float s = b1v[q];
#pragma unroll
      for (int k = 0; k < 7; ++k) s = fmaf(w28[q * 7 + k], swv[k], s);
      o[q] = gelu_cheap(s);
    }
    uint2 pk;
    pk.x = cvt_pk_bf16(o[0], o[1]);
    pk.y = cvt_pk_bf16(o[2], o[3]);
    int r = t + 2;
    int byte = (r << 6) + ((c0 << 1) ^ (((r >> 1) & 3) << 4));
    *(uint2*)((char*)y + byte) = pk;
  }
  __syncthreads();

  // conv2 via MFMA: per wave 64 positions (4 nt tiles), M=32 (2 mt)
  const f32x4 vzero = {0.f, 0.f, 0.f, 0.f};
  f32x4 acc[2][4];
#pragma unroll
  for (int mt = 0; mt < 2; ++mt)
#pragma unroll
    for (int nt = 0; nt < 4; ++nt) acc[mt][nt] = vzero;

#pragma unroll
  for (int kk = 0; kk < 5; ++kk) {
    bf16x8 a0 = *(const bf16x8*)(cw2p + (l16) * 160 + kk * 32 + g16 * 8);
    bf16x8 a1 = *(const bf16x8*)(cw2p + (16 + l16) * 160 + kk * 32 + g16 * 8);
#pragma unroll
    for (int nt = 0; nt < 4; ++nt) {
      int r = waveBase + nt * 16 + l16 + kk;  // y1 row = pos + (kk-2) + 2
      int byte = (r << 6) + ((g16 << 4) ^ (((r >> 1) & 3) << 4));
      bf16x8 bq = *(const bf16x8*)((char*)y + byte);
      acc[0][nt] = __builtin_amdgcn_mfma_f32_16x16x32_bf16(a0, bq, acc[0][nt], 0, 0, 0);
      acc[1][nt] = __builtin_amdgcn_mfma_f32_16x16x32_bf16(a1, bq, acc[1][nt], 0, 0, 0);
    }
  }
  __syncthreads();  // all y1 reads complete before overwrite

  if (tid < 64) {  // zero y2 pad rows 0, 513
    int r = (tid < 32) ? 0 : 513;
    int c = tid & 31;
    int byte = (r << 6) + ((c << 1) ^ (((r >> 1) & 3) << 4));
    *(short*)((char*)y + byte) = 0;
  }
  // y2[pos+1][c_out] = gelu(acc + cb2); pack 4 consecutive c -> b64 write
#pragma unroll
  for (int mt = 0; mt < 2; ++mt) {
    int cb = mt * 16 + g16 * 4;
    const float4 b2v = *(const float4*)(cb2 + cb);
#pragma unroll
    for (int nt = 0; nt < 4; ++nt) {
      int t = waveBase + nt * 16 + l16;
      float o0 = gelu_cheap(acc[mt][nt][0] + b2v.x);
      float o1 = gelu_cheap(acc[mt][nt][1] + b2v.y);
      float o2 = gelu_cheap(acc[mt][nt][2] + b2v.z);
      float o3 = gelu_cheap(acc[mt][nt][3] + b2v.w);
      uint2 pk;
      pk.x = cvt_pk_bf16(o0, o1);
      pk.y = cvt_pk_bf16(o2, o3);
      int r2 = t + 1;
      int byte = (r2 << 6) + ((cb << 1) ^ (((r2 >> 1) & 3) << 4));
      *(uint2*)((char*)y + byte) = pk;
    }
  }
  __syncthreads();

  // conv3 via MFMA: A = cw3p (row 0 only), K=96 (3 taps x 32 ch)
  bf16x8 a3[3];
#pragma unroll
  for (int kk = 0; kk < 3; ++kk)
    a3[kk] = *(const bf16x8*)(cw3p + l16 * 128 + kk * 32 + g16 * 8);

  f32x4 acc3[4];
#pragma unroll
  for (int nt = 0; nt < 4; ++nt) acc3[nt] = vzero;
#pragma unroll
  for (int kk = 0; kk < 3; ++kk) {
#pragma unroll
    for (int nt = 0; nt < 4; ++nt) {
      int r = waveBase + nt * 16 + l16 + kk;  // y2 row for pos t, tap kk
      int byte = (r << 6) + ((g16 << 4) ^ (((r >> 1) & 3) << 4));
      bf16x8 bq = *(const bf16x8*)((char*)y + byte);
      acc3[nt] = __builtin_amdgcn_mfma_f32_16x16x32_bf16(a3[kk], bq, acc3[nt], 0, 0, 0);
    }
  }
  // D row 0 (lanes 0-15, reg 0) holds conv3[t]
  if (g16 == 0) {
#pragma unroll
    for (int nt = 0; nt < 4; ++nt) r3s[waveBase + nt * 16 + l16] = acc3[nt][0];
  }
  __syncthreads();

  const float scale = scales[ids[b]];
  const float c3b = cb3[0];
  {
    int t = tid;
    out[(size_t)b * 512 + t] = (sw[t + 3] + r3s[t] + c3b) * scale;
  }
}

// --------------------------- launch ----------------------------------------
extern "C" void kernel_launch(void* const* d_in, const int* in_sizes, int n_in,
                              void* d_out, int out_size, void* d_ws, size_t ws_size,
                              hipStream_t stream) {
  (void)in_sizes; (void)n_in; (void)out_size; (void)ws_size;
  const float* params = (const float*)d_in[0];
  const float* emb    = (const float*)d_in[1];
  const float* W1  = (const float*)d_in[2];
  const float* b1  = (const float*)d_in[3];
  const float* g1  = (const float*)d_in[4];
  const float* be1 = (const float*)d_in[5];
  const float* W2  = (const float*)d_in[6];
  const float* b2  = (const float*)d_in[7];
  const float* g2  = (const float*)d_in[8];
  const float* be2 = (const float*)d_in[9];
  const float* W3  = (const float*)d_in[10];
  const float* b3  = (const float*)d_in[11];
  const float* g3  = (const float*)d_in[12];
  const float* be3 = (const float*)d_in[13];
  const float* Wh  = (const float*)d_in[14];
  const float* bh  = (const float*)d_in[15];
  const float* Wd1 = (const float*)d_in[16];
  const float* bd1 = (const float*)d_in[17];
  const float* Wd2 = (const float*)d_in[18];
  const float* bd2 = (const float*)d_in[19];
  const float* cw1 = (const float*)d_in[20];
  const float* cb1 = (const float*)d_in[21];
  const float* cw2 = (const float*)d_in[22];
  const float* cb2 = (const float*)d_in[23];
  const float* cw3 = (const float*)d_in[24];
  const float* cb3 = (const float*)d_in[25];
  const float* scales = (const float*)d_in[26];
  const int* ids = (const int*)d_in[27];
  float* out = (float*)d_out;

  char* ws = (char*)d_ws;
  size_t off = 0;
  auto alloc = [&](size_t bytes) {
    size_t r = off;
    off += (bytes + 255) & ~(size_t)255;
    return r;
  };
  short* W1t  = (short*)(ws + alloc((size_t)512 * 64 * 2));
  short* W2t  = (short*)(ws + alloc((size_t)512 * 512 * 2));
  short* W3t  = (short*)(ws + alloc((size_t)1024 * 512 * 2));
  short* Wht  = (short*)(ws + alloc((size_t)3 * 512 * 1024 * 2));
  short* Wd1t = (short*)(ws + alloc((size_t)512 * 512 * 2));
  short* Wd2t = (short*)(ws + alloc((size_t)512 * 512 * 2));
  short* cw2p = (short*)(ws + alloc((size_t)32 * 160 * 2));
  short* cw3p = (short*)(ws + alloc((size_t)16 * 128 * 2));
  short* xb   = (short*)(ws + alloc((size_t)8192 * 64 * 2));
  short* bufP = (short*)(ws + alloc((size_t)8192 * 512 * 2));
  short* bufQ = (short*)(ws + alloc((size_t)8192 * 512 * 2));
  short* bufF = (short*)(ws + alloc((size_t)8192 * 1024 * 2));  // feat, later w6 (fp32)
  int*   cntb = (int*)(ws + alloc(64));
  int*   permb = (int*)(ws + alloc((size_t)8192 * 4));
  float* w6 = (float*)bufF;  // feat is dead once GEMM4 completes

  auto gp = [](long tot) { return (int)((tot + 255) / 256); };

  // bucket rows by topology id
  k_zero<<<1, 64, 0, stream>>>(cntb);
  k_count<<<32, 256, 0, stream>>>(ids, cntb);
  k_assign<<<32, 256, 0, stream>>>(ids, cntb, cntb + 4, permb);

  // weight prep (fp32 -> bf16 B^T layout); tiled transpose = coalesced both sides
  prep_wt_pad<<<gp(512 * 64), 256, 0, stream>>>(W1, W1t, 38, 512, 64);
  prep_wt_tile<<<dim3(256, 1), 256, 0, stream>>>(W2, W2t, 512, 512);     // 16*16 tiles
  prep_wt_tile<<<dim3(512, 1), 256, 0, stream>>>(W3, W3t, 512, 1024);    // 32*16
  prep_wt_tile<<<dim3(512, 3), 256, 0, stream>>>(Wh, Wht, 1024, 512);    // 16*32, x3
  prep_wt_tile<<<dim3(256, 1), 256, 0, stream>>>(Wd1, Wd1t, 512, 512);
  prep_wt_tile<<<dim3(256, 1), 256, 0, stream>>>(Wd2, Wd2t, 512, 512);
  prep_cw2<<<gp(32 * 160), 256, 0, stream>>>(cw2, cw2p);
  prep_cw3<<<gp(16 * 128), 256, 0, stream>>>(cw3, cw3p);

  build_x<<<gp(8192L * 64), 256, 0, stream>>>(params, emb, ids, xb);

  // L1: x(64) -> 512, LN+gelu
  gemm16<64, 512, 4, true, true, false, false>
      <<<512, 512, 0, stream>>>(xb, W1t, b1, g1, be1, bufP, nullptr, nullptr);
  // L2: 512 -> 512, LN+gelu
  gemm16<512, 512, 4, true, true, false, false>
      <<<512, 512, 0, stream>>>(bufP, W2t, b2, g2, be2, bufQ, nullptr, nullptr);
  // L3: 512 -> 1024, LN+gelu -> feat
  gemm16<512, 1024, 8, true, true, false, false>
      <<<512, 512, 0, stream>>>(bufQ, W3t, b3, g3, be3, bufF, nullptr, nullptr);
  // L4: gathered per-topology 1024 -> 512 (+bh), bucketed rows
  gemm16<1024, 512, 4, false, false, false, true>
      <<<512, 512, 0, stream>>>(bufF, Wht, bh, nullptr, nullptr, bufP, permb, ids);
  // L5: 512 -> 512, gelu
  gemm16<512, 512, 4, false, true, false, false>
      <<<512, 512, 0, stream>>>(bufP, Wd1t, bd1, nullptr, nullptr, bufQ, nullptr, nullptr);
  // L6: 512 -> 512, fp32 out (w)
  gemm16<512, 512, 4, false, false, true, false>
      <<<512, 512, 0, stream>>>(bufQ, Wd2t, bd2, nullptr, nullptr, w6, nullptr, nullptr);

  // conv stack + residual + per-id scale
  conv_kernel<<<8192, 512, 0, stream>>>(w6, cw1, cb1, cw2p, cb2, cw3p, cb3,
                                        scales, ids, out);
}

// Round 11
// 658.476 us; speedup vs baseline: 1.8705x; 1.0824x over previous
//
#include <hip/hip_runtime.h>
#include <math.h>

// ---------------------------------------------------------------------------
// MultiTopologySurrogate: fused bf16-MFMA pipeline for MI355X (gfx950)
// ---------------------------------------------------------------------------

using bf16x8 = __attribute__((ext_vector_type(8))) short;
using f32x4  = __attribute__((ext_vector_type(4))) float;

static __device__ __forceinline__ short f2bf(float f) {
  union { float f; unsigned u; } v; v.f = f;
  unsigned r = v.u + 0x7fffu + ((v.u >> 16) & 1u);  // RNE
  return (short)(r >> 16);
}
// pack two f32 -> two bf16 (RNE) in one instruction
static __device__ __forceinline__ unsigned cvt_pk_bf16(float lo, float hi) {
  unsigned r;
  asm("v_cvt_pk_bf16_f32 %0, %1, %2" : "=v"(r) : "v"(lo), "v"(hi));
  return r;
}
// tanh-form gelu, algebraically reduced: 0.5x(1+tanh(u)) = x/(1+exp(-2u))
static __device__ __forceinline__ float gelu_cheap(float x) {
  const float c1 = -2.3022077f;
  const float c3 = -0.10294858f;
  float xx = x * x;
  float z = x * fmaf(c3, xx, c1);
  float e = __builtin_amdgcn_exp2f(z);
  float r = __builtin_amdgcn_rcpf(1.f + e);
  return x * r;
}

// --------------------------- bucket-by-id kernels ---------------------------
__global__ void k_zero(int* c) { if (threadIdx.x < 8) c[threadIdx.x] = 0; }

__global__ void k_count(const int* __restrict__ ids, int* __restrict__ cnt) {
  int i = blockIdx.x * 256 + threadIdx.x;
  if (i < 8192) atomicAdd(&cnt[ids[i]], 1);
}

__global__ void k_assign(const int* __restrict__ ids, const int* __restrict__ cnt,
                         int* __restrict__ cur, int* __restrict__ perm) {
  int i = blockIdx.x * 256 + threadIdx.x;
  if (i >= 8192) return;
  int t = ids[i];
  int base = 0;
  if (t > 0) base += cnt[0];
  if (t > 1) base += cnt[1];
  int pos = base + atomicAdd(&cur[t], 1);
  perm[pos] = i;
}

// ---------------- weight prep (fp32 -> bf16 B^T layout) ---------------------
__global__ void prep_wt_pad(const float* __restrict__ W, short* __restrict__ Wt,
                            int K, int N, int Kpad) {
  int i = blockIdx.x * 256 + threadIdx.x;
  if (i >= N * Kpad) return;
  int n = i / Kpad, k = i - n * Kpad;
  float v = (k < K) ? W[(size_t)k * N + n] : 0.f;
  Wt[i] = f2bf(v);
}

// tiled transpose: W[K][N] fp32 -> Wt[N][K] bf16, coalesced read AND write.
__global__ void prep_wt_tile(const float* __restrict__ W, short* __restrict__ Wt,
                             int K, int N) {
  int ntk = K >> 5;
  int tile = blockIdx.x;
  int nb = tile / ntk, kb = tile - nb * ntk;
  const float* Wb = W + (size_t)blockIdx.y * K * N;
  short* Wtb = Wt + (size_t)blockIdx.y * K * N;
  __shared__ float t[32][33];
  int j = threadIdx.x & 31, i0 = threadIdx.x >> 5;
#pragma unroll
  for (int q = 0; q < 4; ++q) {
    int i = i0 + q * 8;
    t[i][j] = Wb[(size_t)(kb * 32 + i) * N + nb * 32 + j];
  }
  __syncthreads();
#pragma unroll
  for (int q = 0; q < 4; ++q) {
    int i = i0 + q * 8;
    Wtb[(size_t)(nb * 32 + i) * K + kb * 32 + j] = f2bf(t[j][i]);
  }
}

// cw2p[c_out][tap*32 + c_in] = cw2[c_out][c_in][tap]   (K=160 flattened)
__global__ void prep_cw2(const float* __restrict__ cw2, short* __restrict__ cw2p) {
  int i = blockIdx.x * 256 + threadIdx.x;
  if (i >= 32 * 160) return;
  int co = i / 160, j = i - co * 160;
  int tap = j >> 5, ci = j & 31;
  cw2p[i] = f2bf(cw2[(co * 32 + ci) * 5 + tap]);
}

// cw3p[16][128]: row 0 = cw3 flattened [tap*32+c], rows 1-15 zero, tap 3 zero
__global__ void prep_cw3(const float* __restrict__ cw3, short* __restrict__ cw3p) {
  int i = blockIdx.x * 256 + threadIdx.x;
  if (i >= 16 * 128) return;
  int m = i >> 7, j = i & 127;
  int kk = j >> 5, c = j & 31;
  float v = (m == 0 && kk < 3) ? cw3[c * 3 + kk] : 0.f;
  cw3p[i] = f2bf(v);
}

// --------------------------- input featurization ----------------------------
__global__ void build_x(const float* __restrict__ params, const float* __restrict__ emb,
                        const int* __restrict__ ids, short* __restrict__ xb) {
  int i = blockIdx.x * 256 + threadIdx.x;
  if (i >= 8192 * 64) return;
  int row = i >> 6, c = i & 63;
  float v;
  const float lo[6] = {1e-05f, 4.7e-05f, 2.0f, 5.0f, 50000.0f, 0.2f};
  const float hi[6] = {0.00047f, 0.001f, 100.0f, 24.0f, 500000.0f, 0.8f};
  const int lg[6] = {1, 1, 0, 0, 1, 0};
  if (c < 6) {
    float pv = params[row * 6 + c];
    if (lg[c]) v = (logf(pv) - logf(lo[c])) / (logf(hi[c]) - logf(lo[c]));
    else       v = (pv - lo[c]) / (hi[c] - lo[c]);
    v = fminf(fmaxf(v, 0.f), 1.f);
  } else if (c < 38) {
    v = emb[ids[row] * 32 + (c - 6)];
  } else v = 0.f;
  xb[i] = f2bf(v);
}

// ------------------- LN-GEMM: 32 rows x full N per block ---------------------
// grid = B/32 = 256. 8 waves x NTW col-tiles. 2 MFMA per B-load.
// MFMA 16x16x32: A lane l -> A[l&15][(l>>4)*8+j]; B lane l -> B[(l>>4)*8+j][l&15];
// D: col=l&15, row=(l>>4)*4+reg.
template<int K, int N, int NTW, bool DO_LN, bool DO_GELU>
__global__ __launch_bounds__(512, 4) void gemm32(
    const short* __restrict__ A, const short* __restrict__ Wt,
    const float* __restrict__ bias, const float* __restrict__ gam,
    const float* __restrict__ bet, short* __restrict__ outp) {
  const int tid = threadIdx.x;
  const int wave = tid >> 6;
  const int lane = tid & 63;
  const int g16 = lane >> 4;
  const int l16 = lane & 15;
  const int rowBase = blockIdx.x * 32;
  const int colBase = wave * (NTW * 16);

  __shared__ float sPart[32][8][2];
  __shared__ float sStat[32][2];

  size_t aoff[2];
#pragma unroll
  for (int mt = 0; mt < 2; ++mt)
    aoff[mt] = (size_t)(rowBase + mt * 16 + l16) * K + g16 * 8;
  size_t boff[NTW];
#pragma unroll
  for (int nt = 0; nt < NTW; ++nt)
    boff[nt] = (size_t)(colBase + nt * 16 + l16) * K + g16 * 8;

  const f32x4 vzero = {0.f, 0.f, 0.f, 0.f};
  f32x4 acc[2][NTW];
#pragma unroll
  for (int mt = 0; mt < 2; ++mt)
#pragma unroll
    for (int nt = 0; nt < NTW; ++nt) acc[mt][nt] = vzero;

  for (int kk = 0; kk < K / 32; ++kk) {
    bf16x8 a0 = *(const bf16x8*)(A + aoff[0] + kk * 32);
    bf16x8 a1 = *(const bf16x8*)(A + aoff[1] + kk * 32);
#pragma unroll
    for (int nt = 0; nt < NTW; ++nt) {
      bf16x8 bq = *(const bf16x8*)(Wt + boff[nt] + kk * 32);
      acc[0][nt] = __builtin_amdgcn_mfma_f32_16x16x32_bf16(a0, bq, acc[0][nt], 0, 0, 0);
      acc[1][nt] = __builtin_amdgcn_mfma_f32_16x16x32_bf16(a1, bq, acc[1][nt], 0, 0, 0);
    }
  }

  // bias add (precedes LN stats)
#pragma unroll
  for (int nt = 0; nt < NTW; ++nt) {
    float bv = bias[colBase + nt * 16 + l16];
#pragma unroll
    for (int mt = 0; mt < 2; ++mt)
#pragma unroll
      for (int r = 0; r < 4; ++r) acc[mt][nt][r] += bv;
  }

  if (DO_LN) {
#pragma unroll
    for (int mt = 0; mt < 2; ++mt) {
#pragma unroll
      for (int r = 0; r < 4; ++r) {
        float s = 0.f, q = 0.f;
#pragma unroll
        for (int nt = 0; nt < NTW; ++nt) {
          float x = acc[mt][nt][r];
          s += x; q += x * x;
        }
#pragma unroll
        for (int m = 1; m < 16; m <<= 1) {
          s += __shfl_xor(s, m);
          q += __shfl_xor(q, m);
        }
        if (l16 == 0) {
          int row = mt * 16 + g16 * 4 + r;
          sPart[row][wave][0] = s;
          sPart[row][wave][1] = q;
        }
      }
    }
    __syncthreads();
    if (tid < 32) {
      float s = 0.f, q = 0.f;
#pragma unroll
      for (int w = 0; w < 8; ++w) { s += sPart[tid][w][0]; q += sPart[tid][w][1]; }
      float mean = s / (float)N;
      float var = q / (float)N - mean * mean;
      sStat[tid][0] = mean;
      sStat[tid][1] = rsqrtf(var + 1e-5f);
    }
    __syncthreads();
  }

#pragma unroll
  for (int nt = 0; nt < NTW; ++nt) {
    int col = colBase + nt * 16 + l16;
    float gv = DO_LN ? gam[col] : 0.f;
    float bev = DO_LN ? bet[col] : 0.f;
#pragma unroll
    for (int mt = 0; mt < 2; ++mt)
#pragma unroll
      for (int r = 0; r < 4; ++r) {
        int row = mt * 16 + g16 * 4 + r;
        float x = acc[mt][nt][r];
        if (DO_LN) x = (x - sStat[row][0]) * sStat[row][1] * gv + bev;
        if (DO_GELU) x = gelu_cheap(x);
        outp[(size_t)(rowBase + row) * N + col] = f2bf(x);
      }
  }
}

// ---------------- tail GEMM: 64 rows x 128 cols per block --------------------
// grid = (B/64)*(N/128). 8 waves as 2(row) x 4(col); wave tile 32x32.
// Per k-step: 2 A + 2 B loads, 4 MFMA. 4x less weight re-read than 16-row.
template<int K, int N, bool DO_GELU, bool OUT_F32, bool GATHER>
__global__ __launch_bounds__(512, 4) void gemm64(
    const short* __restrict__ A, const short* __restrict__ Wt,
    const float* __restrict__ bias, void* __restrict__ outp,
    const int* __restrict__ perm, const int* __restrict__ ids) {
  const int tid = threadIdx.x;
  const int wave = tid >> 6;
  const int lane = tid & 63;
  const int g16 = lane >> 4;
  const int l16 = lane & 15;
  const int wr = wave >> 2;          // row half (0..1)
  const int wc = wave & 3;           // col quarter (0..3)
  const int nColB = N / 128;
  const int brow = (blockIdx.x / nColB) * 64;
  const int bcol = (blockIdx.x % nColB) * 128;

  __shared__ int sPerm[64];
  __shared__ int sId[64];
  __shared__ int sFlag[3];

  if (GATHER) {
    if (tid < 64) {
      int pr = perm[brow + tid];
      sPerm[tid] = pr;
      sId[tid] = ids[pr];
    }
    __syncthreads();
    if (tid < 3) {
      int f = 0;
      for (int i = 0; i < 64; ++i) f |= (sId[i] == tid) ? 1 : 0;
      sFlag[tid] = f;
    }
    __syncthreads();
  }

  size_t aoff[2];
#pragma unroll
  for (int mt = 0; mt < 2; ++mt) {
    int lrow = wr * 32 + mt * 16 + l16;
    int arow = GATHER ? sPerm[lrow] : (brow + lrow);
    aoff[mt] = (size_t)arow * K + g16 * 8;
  }
  size_t boff[2];
#pragma unroll
  for (int nt = 0; nt < 2; ++nt)
    boff[nt] = (size_t)(bcol + wc * 32 + nt * 16 + l16) * K + g16 * 8;

  const f32x4 vzero = {0.f, 0.f, 0.f, 0.f};
  const int TMAX = GATHER ? 3 : 1;
  for (int t = 0; t < TMAX; ++t) {
    if (GATHER && !sFlag[t]) continue;
    const short* Wtt = Wt + (GATHER ? (size_t)t * N * K : 0);
    const float* bt = bias + (GATHER ? t * N : 0);

    f32x4 acc[2][2];
#pragma unroll
    for (int mt = 0; mt < 2; ++mt)
#pragma unroll
      for (int nt = 0; nt < 2; ++nt) acc[mt][nt] = vzero;

    for (int kk = 0; kk < K / 32; ++kk) {
      bf16x8 a0 = *(const bf16x8*)(A + aoff[0] + kk * 32);
      bf16x8 a1 = *(const bf16x8*)(A + aoff[1] + kk * 32);
      bf16x8 b0 = *(const bf16x8*)(Wtt + boff[0] + kk * 32);
      bf16x8 b1 = *(const bf16x8*)(Wtt + boff[1] + kk * 32);
      acc[0][0] = __builtin_amdgcn_mfma_f32_16x16x32_bf16(a0, b0, acc[0][0], 0, 0, 0);
      acc[0][1] = __builtin_amdgcn_mfma_f32_16x16x32_bf16(a0, b1, acc[0][1], 0, 0, 0);
      acc[1][0] = __builtin_amdgcn_mfma_f32_16x16x32_bf16(a1, b0, acc[1][0], 0, 0, 0);
      acc[1][1] = __builtin_amdgcn_mfma_f32_16x16x32_bf16(a1, b1, acc[1][1], 0, 0, 0);
    }

    float bv[2];
#pragma unroll
    for (int nt = 0; nt < 2; ++nt) bv[nt] = bt[bcol + wc * 32 + nt * 16 + l16];

#pragma unroll
    for (int mt = 0; mt < 2; ++mt)
#pragma unroll
      for (int nt = 0; nt < 2; ++nt) {
        int col = bcol + wc * 32 + nt * 16 + l16;
#pragma unroll
        for (int r = 0; r < 4; ++r) {
          int lrow = wr * 32 + mt * 16 + g16 * 4 + r;
          if (GATHER && sId[lrow] != t) continue;
          float x = acc[mt][nt][r] + bv[nt];
          if (DO_GELU) x = gelu_cheap(x);
          size_t grow = GATHER ? (size_t)sPerm[lrow] : (size_t)(brow + lrow);
          if (OUT_F32) ((float*)outp)[grow * N + col] = x;
          else ((short*)outp)[grow * N + col] = f2bf(x);
        }
      }
  }
}

// --------------------------- conv stack (unchanged from R10) -----------------
__global__ __launch_bounds__(512, 4) void conv_kernel(
    const float* __restrict__ w6, const float* __restrict__ cw1,
    const float* __restrict__ cb1, const short* __restrict__ cw2p,
    const float* __restrict__ cb2, const short* __restrict__ cw3p,
    const float* __restrict__ cb3, const float* __restrict__ scales,
    const int* __restrict__ ids, float* __restrict__ out) {
  const int b = blockIdx.x;
  const int tid = threadIdx.x;
  const int wave = tid >> 6, lane = tid & 63;
  const int g16 = lane >> 4, l16 = lane & 15;
  const int waveBase = wave * 64;

  __shared__ float sw[520];
  __shared__ __align__(16) short y[516 * 32];
  __shared__ float r3s[512];

  const int c0 = (tid & 7) * 4;
  float w28[28];
  {
    const float4* wp = (const float4*)(cw1 + c0 * 7);
#pragma unroll
    for (int m = 0; m < 7; ++m) {
      float4 v = wp[m];
      w28[m * 4 + 0] = v.x; w28[m * 4 + 1] = v.y;
      w28[m * 4 + 2] = v.z; w28[m * 4 + 3] = v.w;
    }
  }
  const float4 bias1 = *(const float4*)(cb1 + c0);

  const float* wr = w6 + (size_t)b * 512;
  for (int i = tid; i < 519; i += 512) {
    int t = i - 3;
    sw[i] = (t >= 0 && t < 512) ? wr[t] : 0.f;
  }
  if (tid >= 384 && tid < 512) {
    int i = tid - 384;
    int rr = i >> 5;
    int r = (rr < 2) ? rr : (512 + rr);
    int c = i & 31;
    int byte = (r << 6) + ((c << 1) ^ (((r >> 1) & 3) << 4));
    *(short*)((char*)y + byte) = 0;
  }
  __syncthreads();

  const float b1v[4] = {bias1.x, bias1.y, bias1.z, bias1.w};
#pragma unroll
  for (int it = 0; it < 8; ++it) {
    int t = (tid >> 3) + it * 64;
    float swv[7];
#pragma unroll
    for (int k = 0; k < 7; ++k) swv[k] = sw[t + k];
    float o[4];
#pragma unroll
    for (int q = 0; q < 4; ++q) {
      float s = b1v[q];
#pragma unroll
      for (int k = 0; k < 7; ++k) s = fmaf(w28[q * 7 + k], swv[k], s);
      o[q] = gelu_cheap(s);
    }
    uint2 pk;
    pk.x = cvt_pk_bf16(o[0], o[1]);
    pk.y = cvt_pk_bf16(o[2], o[3]);
    int r = t + 2;
    int byte = (r << 6) + ((c0 << 1) ^ (((r >> 1) & 3) << 4));
    *(uint2*)((char*)y + byte) = pk;
  }
  __syncthreads();

  const f32x4 vzero = {0.f, 0.f, 0.f, 0.f};
  f32x4 acc[2][4];
#pragma unroll
  for (int mt = 0; mt < 2; ++mt)
#pragma unroll
    for (int nt = 0; nt < 4; ++nt) acc[mt][nt] = vzero;

#pragma unroll
  for (int kk = 0; kk < 5; ++kk) {
    bf16x8 a0 = *(const bf16x8*)(cw2p + (l16) * 160 + kk * 32 + g16 * 8);
    bf16x8 a1 = *(const bf16x8*)(cw2p + (16 + l16) * 160 + kk * 32 + g16 * 8);
#pragma unroll
    for (int nt = 0; nt < 4; ++nt) {
      int r = waveBase + nt * 16 + l16 + kk;
      int byte = (r << 6) + ((g16 << 4) ^ (((r >> 1) & 3) << 4));
      bf16x8 bq = *(const bf16x8*)((char*)y + byte);
      acc[0][nt] = __builtin_amdgcn_mfma_f32_16x16x32_bf16(a0, bq, acc[0][nt], 0, 0, 0);
      acc[1][nt] = __builtin_amdgcn_mfma_f32_16x16x32_bf16(a1, bq, acc[1][nt], 0, 0, 0);
    }
  }
  __syncthreads();

  if (tid < 64) {
    int r = (tid < 32) ? 0 : 513;
    int c = tid & 31;
    int byte = (r << 6) + ((c << 1) ^ (((r >> 1) & 3) << 4));
    *(short*)((char*)y + byte) = 0;
  }
#pragma unroll
  for (int mt = 0; mt < 2; ++mt) {
    int cb = mt * 16 + g16 * 4;
    const float4 b2v = *(const float4*)(cb2 + cb);
#pragma unroll
    for (int nt = 0; nt < 4; ++nt) {
      int t = waveBase + nt * 16 + l16;
      float o0 = gelu_cheap(acc[mt][nt][0] + b2v.x);
      float o1 = gelu_cheap(acc[mt][nt][1] + b2v.y);
      float o2 = gelu_cheap(acc[mt][nt][2] + b2v.z);
      float o3 = gelu_cheap(acc[mt][nt][3] + b2v.w);
      uint2 pk;
      pk.x = cvt_pk_bf16(o0, o1);
      pk.y = cvt_pk_bf16(o2, o3);
      int r2 = t + 1;
      int byte = (r2 << 6) + ((cb << 1) ^ (((r2 >> 1) & 3) << 4));
      *(uint2*)((char*)y + byte) = pk;
    }
  }
  __syncthreads();

  bf16x8 a3[3];
#pragma unroll
  for (int kk = 0; kk < 3; ++kk)
    a3[kk] = *(const bf16x8*)(cw3p + l16 * 128 + kk * 32 + g16 * 8);

  f32x4 acc3[4];
#pragma unroll
  for (int nt = 0; nt < 4; ++nt) acc3[nt] = vzero;
#pragma unroll
  for (int kk = 0; kk < 3; ++kk) {
#pragma unroll
    for (int nt = 0; nt < 4; ++nt) {
      int r = waveBase + nt * 16 + l16 + kk;
      int byte = (r << 6) + ((g16 << 4) ^ (((r >> 1) & 3) << 4));
      bf16x8 bq = *(const bf16x8*)((char*)y + byte);
      acc3[nt] = __builtin_amdgcn_mfma_f32_16x16x32_bf16(a3[kk], bq, acc3[nt], 0, 0, 0);
    }
  }
  if (g16 == 0) {
#pragma unroll
    for (int nt = 0; nt < 4; ++nt) r3s[waveBase + nt * 16 + l16] = acc3[nt][0];
  }
  __syncthreads();

  const float scale = scales[ids[b]];
  const float c3b = cb3[0];
  {
    int t = tid;
    out[(size_t)b * 512 + t] = (sw[t + 3] + r3s[t] + c3b) * scale;
  }
}

// --------------------------- launch ----------------------------------------
extern "C" void kernel_launch(void* const* d_in, const int* in_sizes, int n_in,
                              void* d_out, int out_size, void* d_ws, size_t ws_size,
                              hipStream_t stream) {
  (void)in_sizes; (void)n_in; (void)out_size; (void)ws_size;
  const float* params = (const float*)d_in[0];
  const float* emb    = (const float*)d_in[1];
  const float* W1  = (const float*)d_in[2];
  const float* b1  = (const float*)d_in[3];
  const float* g1  = (const float*)d_in[4];
  const float* be1 = (const float*)d_in[5];
  const float* W2  = (const float*)d_in[6];
  const float* b2  = (const float*)d_in[7];
  const float* g2  = (const float*)d_in[8];
  const float* be2 = (const float*)d_in[9];
  const float* W3  = (const float*)d_in[10];
  const float* b3  = (const float*)d_in[11];
  const float* g3  = (const float*)d_in[12];
  const float* be3 = (const float*)d_in[13];
  const float* Wh  = (const float*)d_in[14];
  const float* bh  = (const float*)d_in[15];
  const float* Wd1 = (const float*)d_in[16];
  const float* bd1 = (const float*)d_in[17];
  const float* Wd2 = (const float*)d_in[18];
  const float* bd2 = (const float*)d_in[19];
  const float* cw1 = (const float*)d_in[20];
  const float* cb1 = (const float*)d_in[21];
  const float* cw2 = (const float*)d_in[22];
  const float* cb2 = (const float*)d_in[23];
  const float* cw3 = (const float*)d_in[24];
  const float* cb3 = (const float*)d_in[25];
  const float* scales = (const float*)d_in[26];
  const int* ids = (const int*)d_in[27];
  float* out = (float*)d_out;

  char* ws = (char*)d_ws;
  size_t off = 0;
  auto alloc = [&](size_t bytes) {
    size_t r = off;
    off += (bytes + 255) & ~(size_t)255;
    return r;
  };
  short* W1t  = (short*)(ws + alloc((size_t)512 * 64 * 2));
  short* W2t  = (short*)(ws + alloc((size_t)512 * 512 * 2));
  short* W3t  = (short*)(ws + alloc((size_t)1024 * 512 * 2));
  short* Wht  = (short*)(ws + alloc((size_t)3 * 512 * 1024 * 2));
  short* Wd1t = (short*)(ws + alloc((size_t)512 * 512 * 2));
  short* Wd2t = (short*)(ws + alloc((size_t)512 * 512 * 2));
  short* cw2p = (short*)(ws + alloc((size_t)32 * 160 * 2));
  short* cw3p = (short*)(ws + alloc((size_t)16 * 128 * 2));
  short* xb   = (short*)(ws + alloc((size_t)8192 * 64 * 2));
  short* bufP = (short*)(ws + alloc((size_t)8192 * 512 * 2));
  short* bufQ = (short*)(ws + alloc((size_t)8192 * 512 * 2));
  short* bufF = (short*)(ws + alloc((size_t)8192 * 1024 * 2));  // feat, later w6 (fp32)
  int*   cntb = (int*)(ws + alloc(64));
  int*   permb = (int*)(ws + alloc((size_t)8192 * 4));
  float* w6 = (float*)bufF;  // feat is dead once GEMM4 completes

  auto gp = [](long tot) { return (int)((tot + 255) / 256); };

  // bucket rows by topology id
  k_zero<<<1, 64, 0, stream>>>(cntb);
  k_count<<<32, 256, 0, stream>>>(ids, cntb);
  k_assign<<<32, 256, 0, stream>>>(ids, cntb, cntb + 4, permb);

  // weight prep (fp32 -> bf16 B^T layout)
  prep_wt_pad<<<gp(512 * 64), 256, 0, stream>>>(W1, W1t, 38, 512, 64);
  prep_wt_tile<<<dim3(256, 1), 256, 0, stream>>>(W2, W2t, 512, 512);
  prep_wt_tile<<<dim3(512, 1), 256, 0, stream>>>(W3, W3t, 512, 1024);
  prep_wt_tile<<<dim3(512, 3), 256, 0, stream>>>(Wh, Wht, 1024, 512);
  prep_wt_tile<<<dim3(256, 1), 256, 0, stream>>>(Wd1, Wd1t, 512, 512);
  prep_wt_tile<<<dim3(256, 1), 256, 0, stream>>>(Wd2, Wd2t, 512, 512);
  prep_cw2<<<gp(32 * 160), 256, 0, stream>>>(cw2, cw2p);
  prep_cw3<<<gp(16 * 128), 256, 0, stream>>>(cw3, cw3p);

  build_x<<<gp(8192L * 64), 256, 0, stream>>>(params, emb, ids, xb);

  // L1-L3: LN layers, 32 rows x full N (grid 256)
  gemm32<64, 512, 4, true, true>
      <<<256, 512, 0, stream>>>(xb, W1t, b1, g1, be1, bufP);
  gemm32<512, 512, 4, true, true>
      <<<256, 512, 0, stream>>>(bufP, W2t, b2, g2, be2, bufQ);
  gemm32<512, 1024, 8, true, true>
      <<<256, 512, 0, stream>>>(bufQ, W3t, b3, g3, be3, bufF);

  // L4-L6: tail layers, 64 rows x 128 cols (grid 512)
  gemm64<1024, 512, false, false, true>
      <<<512, 512, 0, stream>>>(bufF, Wht, bh, bufP, permb, ids);
  gemm64<512, 512, true, false, false>
      <<<512, 512, 0, stream>>>(bufP, Wd1t, bd1, bufQ, nullptr, nullptr);
  gemm64<512, 512, false, true, false>
      <<<512, 512, 0, stream>>>(bufQ, Wd2t, bd2, w6, nullptr, nullptr);

  // conv stack + residual + per-id scale
  conv_kernel<<<8192, 512, 0, stream>>>(w6, cw1, cb1, cw2p, cb2, cw3p, cb3,
                                        scales, ids, out);
}

// Round 13
// 533.346 us; speedup vs baseline: 2.3093x; 1.2346x over previous
//
#include <hip/hip_runtime.h>
#include <math.h>

// ---------------------------------------------------------------------------
// MultiTopologySurrogate: fused bf16-MFMA pipeline for MI355X (gfx950)
// ---------------------------------------------------------------------------

using bf16x8 = __attribute__((ext_vector_type(8))) short;
using f32x4  = __attribute__((ext_vector_type(4))) float;

static __device__ __forceinline__ short f2bf(float f) {
  union { float f; unsigned u; } v; v.f = f;
  unsigned r = v.u + 0x7fffu + ((v.u >> 16) & 1u);  // RNE
  return (short)(r >> 16);
}
static __device__ __forceinline__ unsigned cvt_pk_bf16(float lo, float hi) {
  unsigned r;
  asm("v_cvt_pk_bf16_f32 %0, %1, %2" : "=v"(r) : "v"(lo), "v"(hi));
  return r;
}
// tanh-form gelu, algebraically reduced: 0.5x(1+tanh(u)) = x/(1+exp(-2u))
static __device__ __forceinline__ float gelu_cheap(float x) {
  const float c1 = -2.3022077f;
  const float c3 = -0.10294858f;
  float xx = x * x;
  float z = x * fmaf(c3, xx, c1);
  float e = __builtin_amdgcn_exp2f(z);
  float r = __builtin_amdgcn_rcpf(1.f + e);
  return x * r;
}

// ---------------- bucket by id: single block, ballot ranking -----------------
// 256 threads = 4 waves; wave w owns ids [w*2048, (w+1)*2048).
__global__ void bucket_all(const int* __restrict__ ids, int* __restrict__ perm) {
  __shared__ int wcnt[4][3];
  __shared__ int wstart[4][3];
  const int tid = threadIdx.x;
  const int wave = tid >> 6, lane = tid & 63;
  int c0 = 0, c1 = 0, c2 = 0;
  for (int ch = 0; ch < 32; ++ch) {
    int t = ids[wave * 2048 + ch * 64 + lane];
    unsigned long long b0 = __ballot(t == 0);
    unsigned long long b1 = __ballot(t == 1);
    int n0 = __popcll(b0), n1 = __popcll(b1);
    c0 += n0; c1 += n1; c2 += 64 - n0 - n1;
  }
  if (lane == 0) { wcnt[wave][0] = c0; wcnt[wave][1] = c1; wcnt[wave][2] = c2; }
  __syncthreads();
  if (tid == 0) {
    int tot0 = wcnt[0][0] + wcnt[1][0] + wcnt[2][0] + wcnt[3][0];
    int tot1 = wcnt[0][1] + wcnt[1][1] + wcnt[2][1] + wcnt[3][1];
    int base0 = 0, base1 = tot0, base2 = tot0 + tot1;
    for (int w = 0; w < 4; ++w) {
      wstart[w][0] = base0; base0 += wcnt[w][0];
      wstart[w][1] = base1; base1 += wcnt[w][1];
      wstart[w][2] = base2; base2 += wcnt[w][2];
    }
  }
  __syncthreads();
  int r0 = wstart[wave][0], r1 = wstart[wave][1], r2 = wstart[wave][2];
  for (int ch = 0; ch < 32; ++ch) {
    int i = wave * 2048 + ch * 64 + lane;
    int t = ids[i];
    unsigned long long b0 = __ballot(t == 0);
    unsigned long long b1 = __ballot(t == 1);
    unsigned long long b2 = __ballot(t == 2);
    unsigned long long lm = (1ULL << lane) - 1ULL;
    int pos = (t == 0) ? r0 + __popcll(b0 & lm)
            : (t == 1) ? r1 + __popcll(b1 & lm)
                       : r2 + __popcll(b2 & lm);
    perm[pos] = i;
    r0 += __popcll(b0); r1 += __popcll(b1); r2 += __popcll(b2);
  }
}

// ---------------- mega prep: all weight conversions + build_x ----------------
// 32x32 LDS tile transpose: W[K][N] fp32 -> Wt[N][K] bf16
static __device__ void tile_tr(const float* __restrict__ Wb, short* __restrict__ Wtb,
                               int K, int N, int tile, float (*t)[33]) {
  int ntk = K >> 5;
  int nb = tile / ntk, kb = tile - nb * ntk;
  int j = threadIdx.x & 31, i0 = threadIdx.x >> 5;
#pragma unroll
  for (int q = 0; q < 4; ++q) {
    int i = i0 + q * 8;
    t[i][j] = Wb[(size_t)(kb * 32 + i) * N + nb * 32 + j];
  }
  __syncthreads();
#pragma unroll
  for (int q = 0; q < 4; ++q) {
    int i = i0 + q * 8;
    Wtb[(size_t)(nb * 32 + i) * K + kb * 32 + j] = f2bf(t[j][i]);
  }
}

// block ranges: W2[0,256) W3[256,768) Wh[768,2304) Wd1[2304,2560) Wd2[2560,2816)
//               misc[2816,2972) build_x[2972,5020)
__global__ void prep_mega(
    const float* __restrict__ W1, const float* __restrict__ W2,
    const float* __restrict__ W3, const float* __restrict__ Wh,
    const float* __restrict__ Wd1, const float* __restrict__ Wd2,
    const float* __restrict__ cw2, const float* __restrict__ cw3,
    const float* __restrict__ params, const float* __restrict__ emb,
    const int* __restrict__ ids,
    short* __restrict__ W1t, short* __restrict__ W2t, short* __restrict__ W3t,
    short* __restrict__ Wht, short* __restrict__ Wd1t, short* __restrict__ Wd2t,
    short* __restrict__ cw2p, short* __restrict__ cw3p, short* __restrict__ xb) {
  __shared__ float t[32][33];
  int b = blockIdx.x;
  const int tid = threadIdx.x;
  if (b < 256) { tile_tr(W2, W2t, 512, 512, b, t); return; }
  b -= 256;
  if (b < 512) { tile_tr(W3, W3t, 512, 1024, b, t); return; }
  b -= 512;
  if (b < 1536) {
    int bb = b / 512;
    tile_tr(Wh + (size_t)bb * 524288, Wht + (size_t)bb * 524288, 1024, 512,
            b - bb * 512, t);
    return;
  }
  b -= 1536;
  if (b < 256) { tile_tr(Wd1, Wd1t, 512, 512, b, t); return; }
  b -= 256;
  if (b < 256) { tile_tr(Wd2, Wd2t, 512, 512, b, t); return; }
  b -= 256;
  if (b < 156) {  // misc: W1t pad (32768) + cw2p (5120) + cw3p (2048)
    int idx = b * 256 + tid;
    if (idx < 32768) {
      int n = idx >> 6, k = idx & 63;
      float v = (k < 38) ? W1[(size_t)k * 512 + n] : 0.f;
      W1t[idx] = f2bf(v);
    } else if (idx < 37888) {
      int i = idx - 32768;
      int co = i / 160, j = i - co * 160;
      int tap = j >> 5, ci = j & 31;
      cw2p[i] = f2bf(cw2[(co * 32 + ci) * 5 + tap]);
    } else if (idx < 39936) {
      int i = idx - 37888;
      int m = i >> 7, j = i & 127;
      int kk = j >> 5, c = j & 31;
      cw3p[i] = f2bf((m == 0 && kk < 3) ? cw3[c * 3 + kk] : 0.f);
    }
    return;
  }
  b -= 156;
  {  // build_x: 2048 blocks x 256 = 8192*64
    int i = b * 256 + tid;
    int row = i >> 6, c = i & 63;
    float v;
    const float lo[6] = {1e-05f, 4.7e-05f, 2.0f, 5.0f, 50000.0f, 0.2f};
    const float hi[6] = {0.00047f, 0.001f, 100.0f, 24.0f, 500000.0f, 0.8f};
    const int lg[6] = {1, 1, 0, 0, 1, 0};
    if (c < 6) {
      float pv = params[row * 6 + c];
      if (lg[c]) v = (logf(pv) - logf(lo[c])) / (logf(hi[c]) - logf(lo[c]));
      else       v = (pv - lo[c]) / (hi[c] - lo[c]);
      v = fminf(fmaxf(v, 0.f), 1.f);
    } else if (c < 38) {
      v = emb[ids[row] * 32 + (c - 6)];
    } else v = 0.f;
    xb[i] = f2bf(v);
  }
}

// ------------- LN-GEMM: 32 rows x full N, 1024 threads (16 waves) ------------
// grid = B/32 = 256 -> 1 block/CU, 4 waves/SIMD. Per k-step: 2A+NTW B, 2*NTW MFMA.
// MFMA 16x16x32: A lane l -> A[l&15][(l>>4)*8+j]; B lane l -> B[(l>>4)*8+j][l&15];
// D: col=l&15, row=(l>>4)*4+reg.
template<int K, int N, int NTW>
__global__ __launch_bounds__(1024, 4) void gemm_ln(
    const short* __restrict__ A, const short* __restrict__ Wt,
    const float* __restrict__ bias, const float* __restrict__ gam,
    const float* __restrict__ bet, short* __restrict__ outp) {
  const int tid = threadIdx.x;
  const int wave = tid >> 6;
  const int lane = tid & 63;
  const int g16 = lane >> 4;
  const int l16 = lane & 15;
  const int rowBase = blockIdx.x * 32;
  const int colBase = wave * (NTW * 16);

  __shared__ float sPart[32][16][2];
  __shared__ float sStat[32][2];

  size_t aoff[2];
#pragma unroll
  for (int mt = 0; mt < 2; ++mt)
    aoff[mt] = (size_t)(rowBase + mt * 16 + l16) * K + g16 * 8;
  size_t boff[NTW];
#pragma unroll
  for (int nt = 0; nt < NTW; ++nt)
    boff[nt] = (size_t)(colBase + nt * 16 + l16) * K + g16 * 8;

  const f32x4 vzero = {0.f, 0.f, 0.f, 0.f};
  f32x4 acc[2][NTW];
#pragma unroll
  for (int mt = 0; mt < 2; ++mt)
#pragma unroll
    for (int nt = 0; nt < NTW; ++nt) acc[mt][nt] = vzero;

  for (int kk = 0; kk < K / 32; ++kk) {
    bf16x8 a0 = *(const bf16x8*)(A + aoff[0] + kk * 32);
    bf16x8 a1 = *(const bf16x8*)(A + aoff[1] + kk * 32);
#pragma unroll
    for (int nt = 0; nt < NTW; ++nt) {
      bf16x8 bq = *(const bf16x8*)(Wt + boff[nt] + kk * 32);
      acc[0][nt] = __builtin_amdgcn_mfma_f32_16x16x32_bf16(a0, bq, acc[0][nt], 0, 0, 0);
      acc[1][nt] = __builtin_amdgcn_mfma_f32_16x16x32_bf16(a1, bq, acc[1][nt], 0, 0, 0);
    }
  }

  // bias add (precedes LN stats)
#pragma unroll
  for (int nt = 0; nt < NTW; ++nt) {
    float bv = bias[colBase + nt * 16 + l16];
#pragma unroll
    for (int mt = 0; mt < 2; ++mt)
#pragma unroll
      for (int r = 0; r < 4; ++r) acc[mt][nt][r] += bv;
  }

  // LN stats: per-row partial over this wave's cols, 16-lane shuffle reduce
#pragma unroll
  for (int mt = 0; mt < 2; ++mt) {
#pragma unroll
    for (int r = 0; r < 4; ++r) {
      float s = 0.f, q = 0.f;
#pragma unroll
      for (int nt = 0; nt < NTW; ++nt) {
        float x = acc[mt][nt][r];
        s += x; q += x * x;
      }
#pragma unroll
      for (int m = 1; m < 16; m <<= 1) {
        s += __shfl_xor(s, m);
        q += __shfl_xor(q, m);
      }
      if (l16 == 0) {
        int row = mt * 16 + g16 * 4 + r;
        sPart[row][wave][0] = s;
        sPart[row][wave][1] = q;
      }
    }
  }
  __syncthreads();
  if (tid < 32) {
    float s = 0.f, q = 0.f;
#pragma unroll
    for (int w = 0; w < 16; ++w) { s += sPart[tid][w][0]; q += sPart[tid][w][1]; }
    float mean = s / (float)N;
    float var = q / (float)N - mean * mean;
    sStat[tid][0] = mean;
    sStat[tid][1] = rsqrtf(var + 1e-5f);
  }
  __syncthreads();

#pragma unroll
  for (int nt = 0; nt < NTW; ++nt) {
    int col = colBase + nt * 16 + l16;
    float gv = gam[col];
    float bev = bet[col];
#pragma unroll
    for (int mt = 0; mt < 2; ++mt)
#pragma unroll
      for (int r = 0; r < 4; ++r) {
        int row = mt * 16 + g16 * 4 + r;
        float x = acc[mt][nt][r];
        x = (x - sStat[row][0]) * sStat[row][1] * gv + bev;
        x = gelu_cheap(x);
        outp[(size_t)(rowBase + row) * N + col] = f2bf(x);
      }
  }
}

// ---------------- tail GEMM: 64 rows x 128 cols per block (unchanged) --------
template<int K, int N, bool DO_GELU, bool OUT_F32, bool GATHER>
__global__ __launch_bounds__(512, 4) void gemm64(
    const short* __restrict__ A, const short* __restrict__ Wt,
    const float* __restrict__ bias, void* __restrict__ outp,
    const int* __restrict__ perm, const int* __restrict__ ids) {
  const int tid = threadIdx.x;
  const int wave = tid >> 6;
  const int lane = tid & 63;
  const int g16 = lane >> 4;
  const int l16 = lane & 15;
  const int wr = wave >> 2;
  const int wc = wave & 3;
  const int nColB = N / 128;
  const int brow = (blockIdx.x / nColB) * 64;
  const int bcol = (blockIdx.x % nColB) * 128;

  __shared__ int sPerm[64];
  __shared__ int sId[64];
  __shared__ int sFlag[3];

  if (GATHER) {
    if (tid < 64) {
      int pr = perm[brow + tid];
      sPerm[tid] = pr;
      sId[tid] = ids[pr];
    }
    __syncthreads();
    if (tid < 3) {
      int f = 0;
      for (int i = 0; i < 64; ++i) f |= (sId[i] == tid) ? 1 : 0;
      sFlag[tid] = f;
    }
    __syncthreads();
  }

  size_t aoff[2];
#pragma unroll
  for (int mt = 0; mt < 2; ++mt) {
    int lrow = wr * 32 + mt * 16 + l16;
    int arow = GATHER ? sPerm[lrow] : (brow + lrow);
    aoff[mt] = (size_t)arow * K + g16 * 8;
  }
  size_t boff[2];
#pragma unroll
  for (int nt = 0; nt < 2; ++nt)
    boff[nt] = (size_t)(bcol + wc * 32 + nt * 16 + l16) * K + g16 * 8;

  const f32x4 vzero = {0.f, 0.f, 0.f, 0.f};
  const int TMAX = GATHER ? 3 : 1;
  for (int t = 0; t < TMAX; ++t) {
    if (GATHER && !sFlag[t]) continue;
    const short* Wtt = Wt + (GATHER ? (size_t)t * N * K : 0);
    const float* bt = bias + (GATHER ? t * N : 0);

    f32x4 acc[2][2];
#pragma unroll
    for (int mt = 0; mt < 2; ++mt)
#pragma unroll
      for (int nt = 0; nt < 2; ++nt) acc[mt][nt] = vzero;

    for (int kk = 0; kk < K / 32; ++kk) {
      bf16x8 a0 = *(const bf16x8*)(A + aoff[0] + kk * 32);
      bf16x8 a1 = *(const bf16x8*)(A + aoff[1] + kk * 32);
      bf16x8 b0 = *(const bf16x8*)(Wtt + boff[0] + kk * 32);
      bf16x8 b1 = *(const bf16x8*)(Wtt + boff[1] + kk * 32);
      acc[0][0] = __builtin_amdgcn_mfma_f32_16x16x32_bf16(a0, b0, acc[0][0], 0, 0, 0);
      acc[0][1] = __builtin_amdgcn_mfma_f32_16x16x32_bf16(a0, b1, acc[0][1], 0, 0, 0);
      acc[1][0] = __builtin_amdgcn_mfma_f32_16x16x32_bf16(a1, b0, acc[1][0], 0, 0, 0);
      acc[1][1] = __builtin_amdgcn_mfma_f32_16x16x32_bf16(a1, b1, acc[1][1], 0, 0, 0);
    }

    float bv[2];
#pragma unroll
    for (int nt = 0; nt < 2; ++nt) bv[nt] = bt[bcol + wc * 32 + nt * 16 + l16];

#pragma unroll
    for (int mt = 0; mt < 2; ++mt)
#pragma unroll
      for (int nt = 0; nt < 2; ++nt) {
        int col = bcol + wc * 32 + nt * 16 + l16;
#pragma unroll
        for (int r = 0; r < 4; ++r) {
          int lrow = wr * 32 + mt * 16 + g16 * 4 + r;
          if (GATHER && sId[lrow] != t) continue;
          float x = acc[mt][nt][r] + bv[nt];
          if (DO_GELU) x = gelu_cheap(x);
          size_t grow = GATHER ? (size_t)sPerm[lrow] : (size_t)(brow + lrow);
          if (OUT_F32) ((float*)outp)[grow * N + col] = x;
          else ((short*)outp)[grow * N + col] = f2bf(x);
        }
      }
  }
}

// --------------------------- conv stack (unchanged) --------------------------
__global__ __launch_bounds__(512, 4) void conv_kernel(
    const float* __restrict__ w6, const float* __restrict__ cw1,
    const float* __restrict__ cb1, const short* __restrict__ cw2p,
    const float* __restrict__ cb2, const short* __restrict__ cw3p,
    const float* __restrict__ cb3, const float* __restrict__ scales,
    const int* __restrict__ ids, float* __restrict__ out) {
  const int b = blockIdx.x;
  const int tid = threadIdx.x;
  const int wave = tid >> 6, lane = tid & 63;
  const int g16 = lane >> 4, l16 = lane & 15;
  const int waveBase = wave * 64;

  __shared__ float sw[520];
  __shared__ __align__(16) short y[516 * 32];
  __shared__ float r3s[512];

  const int c0 = (tid & 7) * 4;
  float w28[28];
  {
    const float4* wp = (const float4*)(cw1 + c0 * 7);
#pragma unroll
    for (int m = 0; m < 7; ++m) {
      float4 v = wp[m];
      w28[m * 4 + 0] = v.x; w28[m * 4 + 1] = v.y;
      w28[m * 4 + 2] = v.z; w28[m * 4 + 3] = v.w;
    }
  }
  const float4 bias1 = *(const float4*)(cb1 + c0);

  const float* wr = w6 + (size_t)b * 512;
  for (int i = tid; i < 519; i += 512) {
    int t = i - 3;
    sw[i] = (t >= 0 && t < 512) ? wr[t] : 0.f;
  }
  if (tid >= 384 && tid < 512) {
    int i = tid - 384;
    int rr = i >> 5;
    int r = (rr < 2) ? rr : (512 + rr);
    int c = i & 31;
    int byte = (r << 6) + ((c << 1) ^ (((r >> 1) & 3) << 4));
    *(short*)((char*)y + byte) = 0;
  }
  __syncthreads();

  const float b1v[4] = {bias1.x, bias1.y, bias1.z, bias1.w};
#pragma unroll
  for (int it = 0; it < 8; ++it) {
    int t = (tid >> 3) + it * 64;
    float swv[7];
#pragma unroll
    for (int k = 0; k < 7; ++k) swv[k] = sw[t + k];
    float o[4];
#pragma unroll
    for (int q = 0; q < 4; ++q) {
      float s = b1v[q];
#pragma unroll
      for (int k = 0; k < 7; ++k) s = fmaf(w28[q * 7 + k], swv[k], s);
      o[q] = gelu_cheap(s);
    }
    uint2 pk;
    pk.x = cvt_pk_bf16(o[0], o[1]);
    pk.y = cvt_pk_bf16(o[2], o[3]);
    int r = t + 2;
    int byte = (r << 6) + ((c0 << 1) ^ (((r >> 1) & 3) << 4));
    *(uint2*)((char*)y + byte) = pk;
  }
  __syncthreads();

  const f32x4 vzero = {0.f, 0.f, 0.f, 0.f};
  f32x4 acc[2][4];
#pragma unroll
  for (int mt = 0; mt < 2; ++mt)
#pragma unroll
    for (int nt = 0; nt < 4; ++nt) acc[mt][nt] = vzero;

#pragma unroll
  for (int kk = 0; kk < 5; ++kk) {
    bf16x8 a0 = *(const bf16x8*)(cw2p + (l16) * 160 + kk * 32 + g16 * 8);
    bf16x8 a1 = *(const bf16x8*)(cw2p + (16 + l16) * 160 + kk * 32 + g16 * 8);
#pragma unroll
    for (int nt = 0; nt < 4; ++nt) {
      int r = waveBase + nt * 16 + l16 + kk;
      int byte = (r << 6) + ((g16 << 4) ^ (((r >> 1) & 3) << 4));
      bf16x8 bq = *(const bf16x8*)((char*)y + byte);
      acc[0][nt] = __builtin_amdgcn_mfma_f32_16x16x32_bf16(a0, bq, acc[0][nt], 0, 0, 0);
      acc[1][nt] = __builtin_amdgcn_mfma_f32_16x16x32_bf16(a1, bq, acc[1][nt], 0, 0, 0);
    }
  }
  __syncthreads();

  if (tid < 64) {
    int r = (tid < 32) ? 0 : 513;
    int c = tid & 31;
    int byte = (r << 6) + ((c << 1) ^ (((r >> 1) & 3) << 4));
    *(short*)((char*)y + byte) = 0;
  }
#pragma unroll
  for (int mt = 0; mt < 2; ++mt) {
    int cb = mt * 16 + g16 * 4;
    const float4 b2v = *(const float4*)(cb2 + cb);
#pragma unroll
    for (int nt = 0; nt < 4; ++nt) {
      int t = waveBase + nt * 16 + l16;
      float o0 = gelu_cheap(acc[mt][nt][0] + b2v.x);
      float o1 = gelu_cheap(acc[mt][nt][1] + b2v.y);
      float o2 = gelu_cheap(acc[mt][nt][2] + b2v.z);
      float o3 = gelu_cheap(acc[mt][nt][3] + b2v.w);
      uint2 pk;
      pk.x = cvt_pk_bf16(o0, o1);
      pk.y = cvt_pk_bf16(o2, o3);
      int r2 = t + 1;
      int byte = (r2 << 6) + ((cb << 1) ^ (((r2 >> 1) & 3) << 4));
      *(uint2*)((char*)y + byte) = pk;
    }
  }
  __syncthreads();

  bf16x8 a3[3];
#pragma unroll
  for (int kk = 0; kk < 3; ++kk)
    a3[kk] = *(const bf16x8*)(cw3p + l16 * 128 + kk * 32 + g16 * 8);

  f32x4 acc3[4];
#pragma unroll
  for (int nt = 0; nt < 4; ++nt) acc3[nt] = vzero;
#pragma unroll
  for (int kk = 0; kk < 3; ++kk) {
#pragma unroll
    for (int nt = 0; nt < 4; ++nt) {
      int r = waveBase + nt * 16 + l16 + kk;
      int byte = (r << 6) + ((g16 << 4) ^ (((r >> 1) & 3) << 4));
      bf16x8 bq = *(const bf16x8*)((char*)y + byte);
      acc3[nt] = __builtin_amdgcn_mfma_f32_16x16x32_bf16(a3[kk], bq, acc3[nt], 0, 0, 0);
    }
  }
  if (g16 == 0) {
#pragma unroll
    for (int nt = 0; nt < 4; ++nt) r3s[waveBase + nt * 16 + l16] = acc3[nt][0];
  }
  __syncthreads();

  const float scale = scales[ids[b]];
  const float c3b = cb3[0];
  {
    int t = tid;
    out[(size_t)b * 512 + t] = (sw[t + 3] + r3s[t] + c3b) * scale;
  }
}

// --------------------------- launch ----------------------------------------
extern "C" void kernel_launch(void* const* d_in, const int* in_sizes, int n_in,
                              void* d_out, int out_size, void* d_ws, size_t ws_size,
                              hipStream_t stream) {
  (void)in_sizes; (void)n_in; (void)out_size; (void)ws_size;
  const float* params = (const float*)d_in[0];
  const float* emb    = (const float*)d_in[1];
  const float* W1  = (const float*)d_in[2];
  const float* b1  = (const float*)d_in[3];
  const float* g1  = (const float*)d_in[4];
  const float* be1 = (const float*)d_in[5];
  const float* W2  = (const float*)d_in[6];
  const float* b2  = (const float*)d_in[7];
  const float* g2  = (const float*)d_in[8];
  const float* be2 = (const float*)d_in[9];
  const float* W3  = (const float*)d_in[10];
  const float* b3  = (const float*)d_in[11];
  const float* g3  = (const float*)d_in[12];
  const float* be3 = (const float*)d_in[13];
  const float* Wh  = (const float*)d_in[14];
  const float* bh  = (const float*)d_in[15];
  const float* Wd1 = (const float*)d_in[16];
  const float* bd1 = (const float*)d_in[17];
  const float* Wd2 = (const float*)d_in[18];
  const float* bd2 = (const float*)d_in[19];
  const float* cw1 = (const float*)d_in[20];
  const float* cb1 = (const float*)d_in[21];
  const float* cw2 = (const float*)d_in[22];
  const float* cb2 = (const float*)d_in[23];
  const float* cw3 = (const float*)d_in[24];
  const float* cb3 = (const float*)d_in[25];
  const float* scales = (const float*)d_in[26];
  const int* ids = (const int*)d_in[27];
  float* out = (float*)d_out;

  char* ws = (char*)d_ws;
  size_t off = 0;
  auto alloc = [&](size_t bytes) {
    size_t r = off;
    off += (bytes + 255) & ~(size_t)255;
    return r;
  };
  short* W1t  = (short*)(ws + alloc((size_t)512 * 64 * 2));
  short* W2t  = (short*)(ws + alloc((size_t)512 * 512 * 2));
  short* W3t  = (short*)(ws + alloc((size_t)1024 * 512 * 2));
  short* Wht  = (short*)(ws + alloc((size_t)3 * 512 * 1024 * 2));
  short* Wd1t = (short*)(ws + alloc((size_t)512 * 512 * 2));
  short* Wd2t = (short*)(ws + alloc((size_t)512 * 512 * 2));
  short* cw2p = (short*)(ws + alloc((size_t)32 * 160 * 2));
  short* cw3p = (short*)(ws + alloc((size_t)16 * 128 * 2));
  short* xb   = (short*)(ws + alloc((size_t)8192 * 64 * 2));
  short* bufP = (short*)(ws + alloc((size_t)8192 * 512 * 2));
  short* bufQ = (short*)(ws + alloc((size_t)8192 * 512 * 2));
  short* bufF = (short*)(ws + alloc((size_t)8192 * 1024 * 2));  // feat, later w6 (fp32)
  int*   permb = (int*)(ws + alloc((size_t)8192 * 4));
  float* w6 = (float*)bufF;  // feat is dead once GEMM4 completes

  // 1) bucket rows by topology id (single block)
  bucket_all<<<1, 256, 0, stream>>>(ids, permb);

  // 2) all weight prep + input featurization (one kernel, block-range dispatch)
  prep_mega<<<5020, 256, 0, stream>>>(W1, W2, W3, Wh, Wd1, Wd2, cw2, cw3,
                                      params, emb, ids,
                                      W1t, W2t, W3t, Wht, Wd1t, Wd2t,
                                      cw2p, cw3p, xb);

  // 3) L1-L3: LN layers, 32 rows x full N, 1024 threads (grid 256)
  gemm_ln<64, 512, 2><<<256, 1024, 0, stream>>>(xb, W1t, b1, g1, be1, bufP);
  gemm_ln<512, 512, 2><<<256, 1024, 0, stream>>>(bufP, W2t, b2, g2, be2, bufQ);
  gemm_ln<512, 1024, 4><<<256, 1024, 0, stream>>>(bufQ, W3t, b3, g3, be3, bufF);

  // 4) L4-L6: tail layers, 64 rows x 128 cols (grid 512)
  gemm64<1024, 512, false, false, true>
      <<<512, 512, 0, stream>>>(bufF, Wht, bh, bufP, permb, ids);
  gemm64<512, 512, true, false, false>
      <<<512, 512, 0, stream>>>(bufP, Wd1t, bd1, bufQ, nullptr, nullptr);
  gemm64<512, 512, false, true, false>
      <<<512, 512, 0, stream>>>(bufQ, Wd2t, bd2, w6, nullptr, nullptr);

  // 5) conv stack + residual + per-id scale
  conv_kernel<<<8192, 512, 0, stream>>>(w6, cw1, cb1, cw2p, cb2, cw3p, cb3,
                                        scales, ids, out);
}